// Round 15
// baseline (385.074 us; speedup 1.0000x reference)
//
#include <hip/hip_runtime.h>
#include <hip/hip_bf16.h>
#include <math.h>

#define BB 4
#define NN 1024
#define TT 16
#define FIN 32
#define HH 128
#define LH 64
#define MLPH 32

typedef __attribute__((ext_vector_type(8))) short short8;
typedef __attribute__((ext_vector_type(4))) float f32x4;
typedef unsigned short u16;
typedef unsigned int u32;

union AFu { u32 u[4]; short8 s; };

__device__ __forceinline__ u16 f2b(float f) {
    union { float f; u32 u; } v; v.f = f;
    u32 u = v.u;
    return (u16)((u + 0x7FFFu + ((u >> 16) & 1u)) >> 16);
}
__device__ __forceinline__ float b2f(u16 h) {
    union { u32 u; float f; } v; v.u = ((u32)h) << 16;
    return v.f;
}
__device__ __forceinline__ float frcp(float x) {
    float r; asm("v_rcp_f32 %0, %1" : "=v"(r) : "v"(x)); return r;
}
__device__ __forceinline__ float fsig(float x) {          // 1/(1+e^-x)
    return frcp(1.f + __expf(-x));
}
__device__ __forceinline__ float ftanh(float x) {         // 2*sig(2x)-1
    return __builtin_fmaf(2.f, frcp(1.f + __expf(-2.f * x)), -1.f);
}
__device__ __forceinline__ void gload_lds16(const void* g, void* l) {
    __builtin_amdgcn_global_load_lds((const __attribute__((address_space(1))) unsigned int*)g,
                                     (__attribute__((address_space(3))) unsigned int*)l, 16, 0, 0);
}

// ---------------- precompute (parallel): bf16 weight layouts + fused bias ----------------
__global__ __launch_bounds__(256) void k_pre(const float* __restrict__ W1, const float* __restrict__ W2,
                      const float* __restrict__ W_ih, const float* __restrict__ W_hh,
                      const float* __restrict__ b_ih, const float* __restrict__ b_hh,
                      u16* W1T, u16* W2T, u16* WihB, u16* WhhB, float* bsum) {
    int gi = blockIdx.x * 256 + threadIdx.x;     // 64 blocks -> 16384 threads
    for (int i = gi; i < 128 * 32; i += 16384) { int c = i >> 5, k = i & 31; W1T[i] = f2b(W1[k * 128 + c]); }
    for (int i = gi; i < 128 * 128; i += 16384) { int c = i >> 7, k = i & 127; W2T[i] = f2b(W2[k * 128 + c]); }
    for (int i = gi; i < 256 * 128; i += 16384) WihB[i] = f2b(W_ih[i]);
    for (int i = gi; i < 256 * 64; i += 16384) WhhB[i] = f2b(W_hh[i]);
    if (gi < 256) bsum[gi] = b_ih[gi] + b_hh[gi];
}

// ---------------- adjacency -> bitmask, TRANSPOSED: bmT[b][wd(32)][row(1024)] u32 ----------------
__global__ __launch_bounds__(256) void k_mask(const int* __restrict__ adj, u32* __restrict__ bmT) {
    int gw = (blockIdx.x * 256 + threadIdx.x) >> 6;  // 4096 waves
    int lane = threadIdx.x & 63;
    int base = gw << 4;                              // 16 consecutive words per wave
#pragma unroll 4
    for (int it = 0; it < 16; ++it) {
        int u = base + it;
        unsigned long long m = __ballot(adj[((size_t)u << 6) + lane] > 0);
        if (lane == 0) {
            int g = u & 15;          // 64-j group -> words 2g, 2g+1
            int bi = u >> 4;
            int b = bi >> 10, i = bi & 1023;
            bmT[(((b << 5) + 2 * g) << 10) + i]     = (u32)m;
            bmT[(((b << 5) + 2 * g + 1) << 10) + i] = (u32)(m >> 32);
        }
    }
}

// WhT fragment-linear layout: 8KB per jc: [bt][jc(32)][tc(8)][lane][8e]

// ---------------- GAT layer-1 projection (MFMA): x -> Wh1 frag-linear + s vectors ----------------
__global__ __launch_bounds__(256) void k_projA(const float* __restrict__ x, const u16* __restrict__ W1T,
                                               const float* __restrict__ a1,
                                               u16* __restrict__ WhT, float* __restrict__ ssrc,
                                               float* __restrict__ sdst) {
    __shared__ float tile[64][132];
    __shared__ float sA[256];
    int bt = blockIdx.x >> 4, i0 = (blockIdx.x & 15) << 6;
    int b = bt >> 4, t = bt & 15;
    int tid = threadIdx.x, w = tid >> 6, l = tid & 63;
    int lr = l & 15, lg = l >> 4;
    sA[tid] = a1[tid];
    int i = i0 + 16 * w + lr;
    const float* xp = x + ((size_t)((b << 10) + i) * TT + t) * FIN + 8 * lg;
    float4 x0 = *(const float4*)xp;
    float4 x1 = *(const float4*)(xp + 4);
    short8 af;
    af[0] = (short)f2b(x0.x); af[1] = (short)f2b(x0.y); af[2] = (short)f2b(x0.z); af[3] = (short)f2b(x0.w);
    af[4] = (short)f2b(x1.x); af[5] = (short)f2b(x1.y); af[6] = (short)f2b(x1.z); af[7] = (short)f2b(x1.w);
    f32x4 zz = {0.f, 0.f, 0.f, 0.f};
#pragma unroll
    for (int tc = 0; tc < 8; ++tc) {
        short8 bf = *(const short8*)(W1T + ((16 * tc + lr) << 5) + 8 * lg);
        f32x4 d = __builtin_amdgcn_mfma_f32_16x16x32_bf16(af, bf, zz, 0, 0, 0);
#pragma unroll
        for (int r = 0; r < 4; ++r) tile[16 * w + 4 * lg + r][16 * tc + lr] = d[r];
    }
    __syncthreads();
    if (tid < 128) {
        int r = tid & 63;
        const float* av = sA + ((tid < 64) ? 0 : 128);
        float s = 0.f;
#pragma unroll 4
        for (int c = 0; c < 128; ++c) s += tile[r][c] * av[c];
        ((tid < 64) ? ssrc : sdst)[(bt << 10) + i0 + r] = s;
    }
    {   // write frag-linear: jc = (i0>>5)+hh2, 32 rows each
        int c = tid & 127, hh2 = tid >> 7;
        u16 tmp[32];
#pragma unroll
        for (int j = 0; j < 32; ++j) tmp[j] = f2b(tile[32 * hh2 + j][c]);
        int tc = c >> 4, lr2 = c & 15;
        u16* dst = WhT + (size_t)bt * 131072 + ((i0 >> 5) + hh2) * 4096 + tc * 512 + lr2 * 8;
#pragma unroll
        for (int lg2 = 0; lg2 < 4; ++lg2) *(short8*)(dst + lg2 * 128) = *(const short8*)(tmp + 8 * lg2);
    }
}

// ---------------- GAT layer-2 projection (MFMA): h1 frag-linear -> Wh2 frag-linear + s vectors ----------------
__global__ __launch_bounds__(256) void k_projB(const u16* __restrict__ h1, const u16* __restrict__ W2T,
                                               const float* __restrict__ a2,
                                               u16* __restrict__ WhT, float* __restrict__ ssrc,
                                               float* __restrict__ sdst) {
    __shared__ float tile[64][132];
    __shared__ float sA[256];
    int bt = blockIdx.x >> 4, i0 = (blockIdx.x & 15) << 6;
    int tid = threadIdx.x, w = tid >> 6, l = tid & 63;
    int lr = l & 15, lg = l >> 4;
    sA[tid] = a2[tid];
    const u16* ap = h1 + (size_t)bt * 131072 + ((i0 >> 4) + w) * 2048 + l * 8;
    f32x4 acc[8];
#pragma unroll
    for (int tc = 0; tc < 8; ++tc) acc[tc] = (f32x4){0.f, 0.f, 0.f, 0.f};
#pragma unroll
    for (int ch = 0; ch < 4; ++ch) {
        short8 af = *(const short8*)(ap + ch * 512);
#pragma unroll
        for (int tc = 0; tc < 8; ++tc) {
            short8 bf = *(const short8*)(W2T + ((16 * tc + lr) << 7) + 32 * ch + 8 * lg);
            acc[tc] = __builtin_amdgcn_mfma_f32_16x16x32_bf16(af, bf, acc[tc], 0, 0, 0);
        }
    }
#pragma unroll
    for (int tc = 0; tc < 8; ++tc)
#pragma unroll
        for (int r = 0; r < 4; ++r) tile[16 * w + 4 * lg + r][16 * tc + lr] = acc[tc][r];
    __syncthreads();
    if (tid < 128) {
        int r = tid & 63;
        const float* av = sA + ((tid < 64) ? 0 : 128);
        float s = 0.f;
#pragma unroll 4
        for (int c = 0; c < 128; ++c) s += tile[r][c] * av[c];
        ((tid < 64) ? ssrc : sdst)[(bt << 10) + i0 + r] = s;
    }
    {
        int c = tid & 127, hh2 = tid >> 7;
        u16 tmp[32];
#pragma unroll
        for (int j = 0; j < 32; ++j) tmp[j] = f2b(tile[32 * hh2 + j][c]);
        int tc = c >> 4, lr2 = c & 15;
        u16* dst = WhT + (size_t)bt * 131072 + ((i0 >> 5) + hh2) * 4096 + tc * 512 + lr2 * 8;
#pragma unroll
        for (int lg2 = 0; lg2 < 4; ++lg2) *(short8*)(dst + lg2 * 128) = *(const short8*)(tmp + 8 * lg2);
    }
}

// ================ shared attn main-loop macros ================
#define ATTN_PROLOGUE                                                                \
    __shared__ __align__(16) u16 Bbuf[2][8192];                                      \
    __shared__ __align__(16) float Ej[1024];                                         \
    __shared__ __align__(16) float Fj[1024];                                         \
    int bt = blockIdx.x >> 2, i0b = (blockIdx.x & 3) << 8;                           \
    int b = bt >> 4;                                                                 \
    int tid = threadIdx.x, wv = tid >> 6, l = tid & 63;                              \
    int lr = l & 15, lg = l >> 4;                                                    \
    const u16* wbase = WhT + (size_t)bt * 131072;                                    \
    gload_lds16(wbase + (wv << 10) + l * 8,       &Bbuf[0][(wv << 10)]);             \
    gload_lds16(wbase + (wv << 10) + 512 + l * 8, &Bbuf[0][(wv << 10) + 512]);       \
    for (int k = tid; k < 1024; k += 512) {                                          \
        float sdv = sdst[(bt << 10) + k];                                            \
        Ej[k] = __expf(sdv);                                                         \
        Fj[k] = __expf(0.2f * sdv);                                                  \
    }                                                                                \
    int rb = i0b + (wv << 5);                                                        \
    const u32* mbase = bmT + ((size_t)b << 15);                                      \
    u32 mw0 = mbase[rb + lr];                                                        \
    u32 mw1 = mbase[rb + 16 + lr];                                                   \
    u32 mw2 = mbase[1024 + rb + lr];                                                 \
    u32 mw3 = mbase[1024 + rb + 16 + lr];                                            \
    float si0 = ssrc[(bt << 10) + rb + lr];                                          \
    float si1 = ssrc[(bt << 10) + rb + 16 + lr];                                     \
    float Ei0 = __expf(si0), Fi0 = __expf(0.2f * si0);                               \
    float Ei1 = __expf(si1), Fi1 = __expf(0.2f * si1);                               \
    f32x4 acc[2][8];                                                                 \
    _Pragma("unroll")                                                                \
    for (int rt = 0; rt < 2; ++rt)                                                   \
        _Pragma("unroll")                                                            \
        for (int tc = 0; tc < 8; ++tc) acc[rt][tc] = (f32x4){0.f, 0.f, 0.f, 0.f};    \
    f32x4 accd[2];                                                                   \
    accd[0] = (f32x4){0.f, 0.f, 0.f, 0.f};                                           \
    accd[1] = (f32x4){0.f, 0.f, 0.f, 0.f};                                           \
    short8 bone;                                                                     \
    _Pragma("unroll")                                                                \
    for (int e = 0; e < 8; ++e) bone[e] = (short)0x3F80;                             \
    __syncthreads();

#define PHALF(AF, EI, FI, WW)                                                        \
    {                                                                                \
        u32 byt = ((WW) >> (lg << 3)) & 0xFFu;                                       \
        float pA[8] = {fmaxf((EI) * e0.x, (FI) * f0.x), fmaxf((EI) * e0.y, (FI) * f0.y), \
                       fmaxf((EI) * e0.z, (FI) * f0.z), fmaxf((EI) * e0.w, (FI) * f0.w), \
                       fmaxf((EI) * e1.x, (FI) * f1.x), fmaxf((EI) * e1.y, (FI) * f1.y), \
                       fmaxf((EI) * e1.z, (FI) * f1.z), fmaxf((EI) * e1.w, (FI) * f1.w)}; \
        _Pragma("unroll")                                                            \
        for (int q = 0; q < 4; ++q) {                                                \
            u32 m0 = (u32)(-(int)((byt >> (2 * q)) & 1u));                           \
            u32 m1 = (u32)(-(int)((byt >> (2 * q + 1)) & 1u));                       \
            float p0 = __uint_as_float(__float_as_uint(pA[2 * q]) & m0);             \
            float p1 = __uint_as_float(__float_as_uint(pA[2 * q + 1]) & m1);         \
            asm("v_cvt_pk_bf16_f32 %0, %1, %2" : "=v"(AF.u[q]) : "v"(p0), "v"(p1));  \
        }                                                                            \
    }

#define COMPUTE(JC, CUR, JCL, W0, W1)                                                \
    {                                                                                \
        short8 bfr[8];                                                               \
        _Pragma("unroll")                                                            \
        for (int tc = 0; tc < 8; ++tc)                                               \
            bfr[tc] = *(const short8*)(&Bbuf[CUR][(JCL) * 4096 + tc * 512 + l * 8]); \
        const float* ejp = Ej + ((JC) << 5) + (lg << 3);                             \
        const float* fjp = Fj + ((JC) << 5) + (lg << 3);                             \
        float4 e0 = *(const float4*)ejp, e1 = *(const float4*)(ejp + 4);             \
        float4 f0 = *(const float4*)fjp, f1 = *(const float4*)(fjp + 4);             \
        AFu af0, af1;                                                                \
        PHALF(af0, Ei0, Fi0, W0)                                                     \
        PHALF(af1, Ei1, Fi1, W1)                                                     \
        _Pragma("unroll")                                                            \
        for (int tc = 0; tc < 8; ++tc) {                                             \
            acc[0][tc] = __builtin_amdgcn_mfma_f32_16x16x32_bf16(af0.s, bfr[tc], acc[0][tc], 0, 0, 0); \
            acc[1][tc] = __builtin_amdgcn_mfma_f32_16x16x32_bf16(af1.s, bfr[tc], acc[1][tc], 0, 0, 0); \
        }                                                                            \
        accd[0] = __builtin_amdgcn_mfma_f32_16x16x32_bf16(af0.s, bone, accd[0], 0, 0, 0); \
        accd[1] = __builtin_amdgcn_mfma_f32_16x16x32_bf16(af1.s, bone, accd[1], 0, 0, 0); \
    }

#define ATTN_MAIN_LOOP                                                               \
    for (int c = 0; c < 16; ++c) {                                                   \
        int cur = c & 1;                                                             \
        if (c < 15) {                                                                \
            gload_lds16(wbase + (c + 1) * 8192 + (wv << 10) + l * 8,       &Bbuf[cur ^ 1][(wv << 10)]);       \
            gload_lds16(wbase + (c + 1) * 8192 + (wv << 10) + 512 + l * 8, &Bbuf[cur ^ 1][(wv << 10) + 512]); \
        }                                                                            \
        u32 nw0 = 0, nw1 = 0, nw2 = 0, nw3 = 0;                                      \
        if (c < 15) {                                                                \
            const u32* mp = mbase + ((2 * c + 2) << 10);                             \
            nw0 = mp[rb + lr];        nw1 = mp[rb + 16 + lr];                        \
            nw2 = mp[1024 + rb + lr]; nw3 = mp[1024 + rb + 16 + lr];                 \
        }                                                                            \
        COMPUTE(2 * c,     cur, 0, mw0, mw1)                                         \
        COMPUTE(2 * c + 1, cur, 1, mw2, mw3)                                         \
        mw0 = nw0; mw1 = nw1; mw2 = nw2; mw3 = nw3;                                  \
        __syncthreads();                                                             \
    }

// ---------------- attn layer 1: h out (A-fragment-linear). VGPR capped at 85 via
// launch_bounds(512,6) -> 3 blocks/CU (round-11 compile proven to fit in 84). ----------------
__global__ __launch_bounds__(512, 6) void k_attnH(const u16* __restrict__ WhT, const float* __restrict__ ssrc,
                                                  const float* __restrict__ sdst, const u32* __restrict__ bmT,
                                                  u16* __restrict__ hout) {
    ATTN_PROLOGUE
    ATTN_MAIN_LOOP

    // round-11 epilogue: two passes, 8KB wave-private tiles
    char* hb = (char*)(&Bbuf[0][0]) + ((wv & 3) << 13);
    for (int pass = 0; pass < 2; ++pass) {
        if ((wv >> 2) == pass) {
#pragma unroll
            for (int rt = 0; rt < 2; ++rt) {
                float inv[4];
#pragma unroll
                for (int r = 0; r < 4; ++r) inv[r] = 1.f / accd[rt][r];
#pragma unroll
                for (int tc = 0; tc < 8; ++tc)
#pragma unroll
                    for (int r = 0; r < 4; ++r) {
                        float v = acc[rt][tc][r] * inv[r];
                        v = v > 0.f ? v : (__expf(v) - 1.f);
                        v = v > 0.f ? v : (__expf(v) - 1.f);
                        int row = (rt << 4) + (lg << 2) + r;
                        int col = (tc << 4) + lr;
                        *(u16*)(hb + (row << 8) + ((col << 1) ^ ((row & 7) << 4))) = f2b(v);
                    }
            }
            asm volatile("s_waitcnt lgkmcnt(0)" ::: "memory");
            __builtin_amdgcn_sched_barrier(0);
            int rtile0 = rb >> 4;
            u16* dstb = hout + (size_t)bt * 131072;
#pragma unroll
            for (int rt = 0; rt < 2; ++rt)
#pragma unroll
                for (int ch = 0; ch < 4; ++ch) {
                    int row = (rt << 4) + lr;
                    int colb = (ch << 5) + (lg << 3);
                    short8 v = *(const short8*)(hb + (row << 8) + ((colb << 1) ^ ((row & 7) << 4)));
                    *(short8*)(dstb + (size_t)(rtile0 + rt) * 2048 + ch * 512 + l * 8) = v;
                }
        }
        __syncthreads();
    }
}

// ---------------- attn layer 2: fused Gx = elu2(h) @ W_ih^T + bias ----------------
__global__ __launch_bounds__(512, 2) void k_attnG(const u16* __restrict__ WhT, const float* __restrict__ ssrc,
                                                  const float* __restrict__ sdst, const u32* __restrict__ bmT,
                                                  const u16* __restrict__ WihB, const float* __restrict__ bsum,
                                                  u16* __restrict__ Gx) {
    ATTN_PROLOGUE
    ATTN_MAIN_LOOP

    int t = bt & 15;
    char* hb = (char*)(&Bbuf[0][0]) + (wv << 12);

#define EPI_STORE(RT)                                                                 \
    {                                                                                 \
        float inv[4];                                                                 \
        _Pragma("unroll")                                                             \
        for (int r = 0; r < 4; ++r) inv[r] = 1.f / accd[RT][r];                       \
        _Pragma("unroll")                                                             \
        for (int tc = 0; tc < 8; ++tc)                                                \
            _Pragma("unroll")                                                         \
            for (int r = 0; r < 4; ++r) {                                             \
                float v = acc[RT][tc][r] * inv[r];                                    \
                v = v > 0.f ? v : (__expf(v) - 1.f);                                  \
                v = v > 0.f ? v : (__expf(v) - 1.f);                                  \
                int row = (lg << 2) + r;                                              \
                int col = (tc << 4) + lr;                                             \
                *(u16*)(hb + (row << 8) + ((col << 1) ^ ((row & 7) << 4))) = f2b(v);  \
            }                                                                         \
        asm volatile("s_waitcnt lgkmcnt(0)" ::: "memory");                            \
        __builtin_amdgcn_sched_barrier(0);                                            \
    }

#define EPI_OUT_GX(RT)                                                                \
    {                                                                                 \
        int node = i0b + (wv << 5) + ((RT) << 4);                                     \
        int grpx = (b << 6) + (node >> 4);                                            \
        u16* gdst = Gx + (size_t)t * 1048576 + (size_t)grpx * 4096 + l * 8;           \
        _Pragma("unroll")                                                             \
        for (int half = 0; half < 2; ++half) {                                        \
            f32x4 accg[8];                                                            \
            _Pragma("unroll")                                                         \
            for (int tq = 0; tq < 8; ++tq) accg[tq] = (f32x4){0.f, 0.f, 0.f, 0.f};    \
            _Pragma("unroll")                                                         \
            for (int ch = 0; ch < 4; ++ch) {                                          \
                short8 af2 = *(const short8*)(hb + (lr << 8) + (((ch << 6) + (lg << 4)) ^ ((lr & 7) << 4))); \
                _Pragma("unroll")                                                     \
                for (int tq = 0; tq < 8; ++tq) {                                      \
                    int tc = (half << 3) + tq;                                        \
                    short8 bf = *(const short8*)(WihB + ((16 * tc + lr) << 7) + (ch << 5) + 8 * lg); \
                    accg[tq] = __builtin_amdgcn_mfma_f32_16x16x32_bf16(af2, bf, accg[tq], 0, 0, 0); \
                }                                                                     \
            }                                                                         \
            _Pragma("unroll")                                                         \
            for (int qq = 0; qq < 4; ++qq) {                                          \
                int tc0 = (half << 3) + 2 * qq;                                       \
                short8 v;                                                             \
                _Pragma("unroll")                                                     \
                for (int r = 0; r < 4; ++r) {                                         \
                    v[r]     = (short)f2b(accg[2 * qq][r]     + bsum[(tc0 << 4) + lr]); \
                    v[4 + r] = (short)f2b(accg[2 * qq + 1][r] + bsum[((tc0 + 1) << 4) + lr]); \
                }                                                                     \
                *(short8*)(gdst + ((half << 2) + qq) * 512) = v;                      \
            }                                                                         \
        }                                                                             \
    }

    EPI_STORE(0)
    EPI_OUT_GX(0)
    asm volatile("s_waitcnt lgkmcnt(0)" ::: "memory");   // rt0 tile reads done before overwrite
    __builtin_amdgcn_sched_barrier(0);
    EPI_STORE(1)
    EPI_OUT_GX(1)

#undef EPI_STORE
#undef EPI_OUT_GX
}

#undef ATTN_PROLOGUE
#undef ATTN_MAIN_LOOP
#undef PHALF
#undef COMPUTE

// ---------------- LSTM recurrence: 4 waves/block, wave w owns gate-tiles {w,w+4,w+8,w+12}
// (= i/f/g/o for hidden cols [16w,16w+16)); h exchanged via LDS; fused MLP on wave 0 ----------------
__global__ __launch_bounds__(256, 1) void k_lstm(const u16* __restrict__ Gx, const u16* __restrict__ WhhB,
                                                 const float* __restrict__ Wo1, const float* __restrict__ bo1,
                                                 const float* __restrict__ Wo2, const float* __restrict__ bo2,
                                                 float* __restrict__ out) {
    __shared__ u16 hls[16 * 72];
    __shared__ float hf[16 * 65];
    __shared__ float wo1[64 * 32];
    __shared__ float wo2[32];
    int grp = blockIdx.x;
    int m0 = grp << 4;
    int tid = threadIdx.x, wv = tid >> 6, l = tid & 63;
    int lr = l & 15, lg = l >> 4;
    for (int k = tid; k < 64 * 32; k += 256) wo1[k] = Wo1[k];
    if (tid < 32) wo2[tid] = Wo2[tid];
    for (int k = tid; k < 16 * 72; k += 256) hls[k] = 0;
    short8 bh[4][2];
#pragma unroll
    for (int tq = 0; tq < 4; ++tq)
#pragma unroll
        for (int ch = 0; ch < 2; ++ch)
            bh[tq][ch] = *(const short8*)(WhhB + ((16 * (wv + 4 * tq) + lr) << 6) + 32 * ch + 8 * lg);
    float cst[4], hreg[4];
#pragma unroll
    for (int r = 0; r < 4; ++r) { cst[r] = 0.f; hreg[r] = 0.f; }
    int sub = wv & 1;
    // Gx fragments for this wave: q = (wv>>1) + 2*tq
    const u16* gp = Gx + ((size_t)grp << 12) + ((size_t)(wv >> 1) << 9) + l * 8;
    short8 gx0[4], gx1[4];
#pragma unroll
    for (int tq = 0; tq < 4; ++tq) gx0[tq] = *(const short8*)(gp + tq * 1024);
    __syncthreads();
#pragma unroll
    for (int t = 0; t < TT; ++t) {
        if (t < 15) {     // prefetch next step's fragments
#pragma unroll
            for (int tq = 0; tq < 4; ++tq) {
                short8 v = *(const short8*)(gp + (size_t)(t + 1) * 1048576 + tq * 1024);
                if (t & 1) gx0[tq] = v; else gx1[tq] = v;
            }
        }
        f32x4 acc[4];
#pragma unroll
        for (int tq = 0; tq < 4; ++tq) {
            short8 v = (t & 1) ? gx1[tq] : gx0[tq];
#pragma unroll
            for (int r = 0; r < 4; ++r)
                acc[tq][r] = b2f((u16)v[(sub << 2) + r]);
        }
#pragma unroll
        for (int ch = 0; ch < 2; ++ch) {
            short8 af = *(const short8*)(hls + lr * 72 + 32 * ch + 8 * lg);
#pragma unroll
            for (int tq = 0; tq < 4; ++tq)
                acc[tq] = __builtin_amdgcn_mfma_f32_16x16x32_bf16(af, bh[tq][ch], acc[tq], 0, 0, 0);
        }
#pragma unroll
        for (int r = 0; r < 4; ++r) {
            float iv = fsig(acc[0][r]);
            float fv = fsig(acc[1][r]);
            float gv = ftanh(acc[2][r]);
            float ov = fsig(acc[3][r]);
            float cn = __builtin_fmaf(fv, cst[r], iv * gv);
            cst[r] = cn;
            hreg[r] = ov * ftanh(cn);
        }
        __syncthreads();     // all waves done reading hls
#pragma unroll
        for (int r = 0; r < 4; ++r)
            hls[(4 * lg + r) * 72 + 16 * wv + lr] = f2b(hreg[r]);
        __syncthreads();     // h ready for next step
    }
#pragma unroll
    for (int r = 0; r < 4; ++r)
        hf[(4 * lg + r) * 65 + 16 * wv + lr] = hreg[r];
    __syncthreads();
    if (wv == 0) {
        int r = lr, p = lg;
        float hid[8];
#pragma unroll
        for (int q = 0; q < 8; ++q) hid[q] = bo1[8 * p + q];
        for (int j = 0; j < 64; ++j) {
            float hv = hf[r * 65 + j];
#pragma unroll
            for (int q = 0; q < 8; ++q) hid[q] += hv * wo1[j * 32 + 8 * p + q];
        }
        float po = 0.f;
#pragma unroll
        for (int q = 0; q < 8; ++q) po += fmaxf(hid[q], 0.f) * wo2[8 * p + q];
        po += __shfl_xor(po, 16);
        po += __shfl_xor(po, 32);
        if (p == 0) out[m0 + r] = po + bo2[0];
    }
}

extern "C" void kernel_launch(void* const* d_in, const int* in_sizes, int n_in,
                              void* d_out, int out_size, void* d_ws, size_t ws_size,
                              hipStream_t stream) {
    const float* x    = (const float*)d_in[0];
    const int*   adj  = (const int*)d_in[1];
    const float* W1   = (const float*)d_in[2];
    const float* a1   = (const float*)d_in[3];
    const float* W2   = (const float*)d_in[4];
    const float* a2   = (const float*)d_in[5];
    const float* W_ih = (const float*)d_in[6];
    const float* W_hh = (const float*)d_in[7];
    const float* b_ih = (const float*)d_in[8];
    const float* b_hh = (const float*)d_in[9];
    const float* Wo1  = (const float*)d_in[10];
    const float* bo1  = (const float*)d_in[11];
    const float* Wo2  = (const float*)d_in[12];
    const float* bo2  = (const float*)d_in[13];
    float* out = (float*)d_out;

    char* w = (char*)d_ws;
    const size_t SLOT = (size_t)8388608 * sizeof(u16);   // 16.78 MB
    u16* A  = (u16*)w;
    u16* Bf = (u16*)(w + SLOT);
    u16* C  = (u16*)(w + 2 * SLOT);
    char* sm = w + 3 * SLOT;
    float* s1s = (float*)sm;
    float* s1d = s1s + 65536;
    float* s2s = s1d + 65536;
    float* s2d = s2s + 65536;
    u32* BM  = (u32*)(s2d + 65536);      // 131072 words (512 KB), transposed layout
    u16* W1T = (u16*)(BM + 131072);      // 4096
    u16* W2T = W1T + 4096;               // 16384
    u16* WihB = W2T + 16384;             // 32768
    u16* WhhB = WihB + 32768;            // 16384
    float* BS = (float*)(WhhB + 16384);  // 256
    u16* Gx = Bf;                        // Bf dead after projB; Gx spans Bf..C (33.55 MB)

    k_pre<<<64, 256, 0, stream>>>(W1, W2, W_ih, W_hh, b_ih, b_hh, W1T, W2T, WihB, WhhB, BS);
    k_mask<<<1024, 256, 0, stream>>>(adj, BM);
    k_projA<<<1024, 256, 0, stream>>>(x, W1T, a1, A, s1s, s1d);
    k_attnH<<<256, 512, 0, stream>>>(A, s1s, s1d, BM, Bf);
    k_projB<<<1024, 256, 0, stream>>>(Bf, W2T, a2, C, s2s, s2d);
    k_attnG<<<256, 512, 0, stream>>>(C, s2s, s2d, BM, WihB, BS, Gx);
    k_lstm<<<256, 256, 0, stream>>>(Gx, WhhB, Wo1, bo1, Wo2, bo2, out);
}

// Round 16
// 167.526 us; speedup vs baseline: 2.2986x; 2.2986x over previous
//
#include <hip/hip_runtime.h>
#include <hip/hip_bf16.h>
#include <math.h>

#define BB 4
#define NN 1024
#define TT 16
#define FIN 32
#define HH 128
#define LH 64
#define MLPH 32

typedef __attribute__((ext_vector_type(8))) short short8;
typedef __attribute__((ext_vector_type(4))) float f32x4;
typedef unsigned short u16;
typedef unsigned int u32;

union AFu { u32 u[4]; short8 s; };

__device__ __forceinline__ u16 f2b(float f) {
    union { float f; u32 u; } v; v.f = f;
    u32 u = v.u;
    return (u16)((u + 0x7FFFu + ((u >> 16) & 1u)) >> 16);
}
__device__ __forceinline__ float b2f(u16 h) {
    union { u32 u; float f; } v; v.u = ((u32)h) << 16;
    return v.f;
}
__device__ __forceinline__ float frcp(float x) {
    float r; asm("v_rcp_f32 %0, %1" : "=v"(r) : "v"(x)); return r;
}
__device__ __forceinline__ float fsig(float x) {          // 1/(1+e^-x)
    return frcp(1.f + __expf(-x));
}
__device__ __forceinline__ float ftanh(float x) {         // 2*sig(2x)-1
    return __builtin_fmaf(2.f, frcp(1.f + __expf(-2.f * x)), -1.f);
}
__device__ __forceinline__ void gload_lds16(const void* g, void* l) {
    __builtin_amdgcn_global_load_lds((const __attribute__((address_space(1))) unsigned int*)g,
                                     (__attribute__((address_space(3))) unsigned int*)l, 16, 0, 0);
}

// ---------------- precompute (parallel): bf16 weight layouts + fused bias ----------------
__global__ __launch_bounds__(256) void k_pre(const float* __restrict__ W1, const float* __restrict__ W2,
                      const float* __restrict__ W_ih, const float* __restrict__ W_hh,
                      const float* __restrict__ b_ih, const float* __restrict__ b_hh,
                      u16* W1T, u16* W2T, u16* WihB, u16* WhhB, float* bsum) {
    int gi = blockIdx.x * 256 + threadIdx.x;     // 64 blocks -> 16384 threads
    for (int i = gi; i < 128 * 32; i += 16384) { int c = i >> 5, k = i & 31; W1T[i] = f2b(W1[k * 128 + c]); }
    for (int i = gi; i < 128 * 128; i += 16384) { int c = i >> 7, k = i & 127; W2T[i] = f2b(W2[k * 128 + c]); }
    for (int i = gi; i < 256 * 128; i += 16384) WihB[i] = f2b(W_ih[i]);
    for (int i = gi; i < 256 * 64; i += 16384) WhhB[i] = f2b(W_hh[i]);
    if (gi < 256) bsum[gi] = b_ih[gi] + b_hh[gi];
}

// ---------------- adjacency -> bitmask, TRANSPOSED: bmT[b][wd(32)][row(1024)] u32 ----------------
__global__ __launch_bounds__(256) void k_mask(const int* __restrict__ adj, u32* __restrict__ bmT) {
    int gw = (blockIdx.x * 256 + threadIdx.x) >> 6;  // 4096 waves
    int lane = threadIdx.x & 63;
    int base = gw << 4;                              // 16 consecutive words per wave
#pragma unroll 4
    for (int it = 0; it < 16; ++it) {
        int u = base + it;
        unsigned long long m = __ballot(adj[((size_t)u << 6) + lane] > 0);
        if (lane == 0) {
            int g = u & 15;          // 64-j group -> words 2g, 2g+1
            int bi = u >> 4;
            int b = bi >> 10, i = bi & 1023;
            bmT[(((b << 5) + 2 * g) << 10) + i]     = (u32)m;
            bmT[(((b << 5) + 2 * g + 1) << 10) + i] = (u32)(m >> 32);
        }
    }
}

// WhT fragment-linear layout: 8KB per jc: [bt][jc(32)][tc(8)][lane][8e]

// ---------------- GAT layer-1 projection (MFMA): x -> Wh1 frag-linear + s vectors ----------------
__global__ __launch_bounds__(256) void k_projA(const float* __restrict__ x, const u16* __restrict__ W1T,
                                               const float* __restrict__ a1,
                                               u16* __restrict__ WhT, float* __restrict__ ssrc,
                                               float* __restrict__ sdst) {
    __shared__ float tile[64][132];
    __shared__ float sA[256];
    int bt = blockIdx.x >> 4, i0 = (blockIdx.x & 15) << 6;
    int b = bt >> 4, t = bt & 15;
    int tid = threadIdx.x, w = tid >> 6, l = tid & 63;
    int lr = l & 15, lg = l >> 4;
    sA[tid] = a1[tid];
    int i = i0 + 16 * w + lr;
    const float* xp = x + ((size_t)((b << 10) + i) * TT + t) * FIN + 8 * lg;
    float4 x0 = *(const float4*)xp;
    float4 x1 = *(const float4*)(xp + 4);
    short8 af;
    af[0] = (short)f2b(x0.x); af[1] = (short)f2b(x0.y); af[2] = (short)f2b(x0.z); af[3] = (short)f2b(x0.w);
    af[4] = (short)f2b(x1.x); af[5] = (short)f2b(x1.y); af[6] = (short)f2b(x1.z); af[7] = (short)f2b(x1.w);
    f32x4 zz = {0.f, 0.f, 0.f, 0.f};
#pragma unroll
    for (int tc = 0; tc < 8; ++tc) {
        short8 bf = *(const short8*)(W1T + ((16 * tc + lr) << 5) + 8 * lg);
        f32x4 d = __builtin_amdgcn_mfma_f32_16x16x32_bf16(af, bf, zz, 0, 0, 0);
#pragma unroll
        for (int r = 0; r < 4; ++r) tile[16 * w + 4 * lg + r][16 * tc + lr] = d[r];
    }
    __syncthreads();
    if (tid < 128) {
        int r = tid & 63;
        const float* av = sA + ((tid < 64) ? 0 : 128);
        float s = 0.f;
#pragma unroll 4
        for (int c = 0; c < 128; ++c) s += tile[r][c] * av[c];
        ((tid < 64) ? ssrc : sdst)[(bt << 10) + i0 + r] = s;
    }
    {   // write frag-linear: jc = (i0>>5)+hh2, 32 rows each
        int c = tid & 127, hh2 = tid >> 7;
        u16 tmp[32];
#pragma unroll
        for (int j = 0; j < 32; ++j) tmp[j] = f2b(tile[32 * hh2 + j][c]);
        int tc = c >> 4, lr2 = c & 15;
        u16* dst = WhT + (size_t)bt * 131072 + ((i0 >> 5) + hh2) * 4096 + tc * 512 + lr2 * 8;
#pragma unroll
        for (int lg2 = 0; lg2 < 4; ++lg2) *(short8*)(dst + lg2 * 128) = *(const short8*)(tmp + 8 * lg2);
    }
}

// ---------------- GAT layer-2 projection (MFMA): h1 frag-linear -> Wh2 frag-linear + s vectors ----------------
__global__ __launch_bounds__(256) void k_projB(const u16* __restrict__ h1, const u16* __restrict__ W2T,
                                               const float* __restrict__ a2,
                                               u16* __restrict__ WhT, float* __restrict__ ssrc,
                                               float* __restrict__ sdst) {
    __shared__ float tile[64][132];
    __shared__ float sA[256];
    int bt = blockIdx.x >> 4, i0 = (blockIdx.x & 15) << 6;
    int tid = threadIdx.x, w = tid >> 6, l = tid & 63;
    int lr = l & 15, lg = l >> 4;
    sA[tid] = a2[tid];
    const u16* ap = h1 + (size_t)bt * 131072 + ((i0 >> 4) + w) * 2048 + l * 8;
    f32x4 acc[8];
#pragma unroll
    for (int tc = 0; tc < 8; ++tc) acc[tc] = (f32x4){0.f, 0.f, 0.f, 0.f};
#pragma unroll
    for (int ch = 0; ch < 4; ++ch) {
        short8 af = *(const short8*)(ap + ch * 512);
#pragma unroll
        for (int tc = 0; tc < 8; ++tc) {
            short8 bf = *(const short8*)(W2T + ((16 * tc + lr) << 7) + 32 * ch + 8 * lg);
            acc[tc] = __builtin_amdgcn_mfma_f32_16x16x32_bf16(af, bf, acc[tc], 0, 0, 0);
        }
    }
#pragma unroll
    for (int tc = 0; tc < 8; ++tc)
#pragma unroll
        for (int r = 0; r < 4; ++r) tile[16 * w + 4 * lg + r][16 * tc + lr] = acc[tc][r];
    __syncthreads();
    if (tid < 128) {
        int r = tid & 63;
        const float* av = sA + ((tid < 64) ? 0 : 128);
        float s = 0.f;
#pragma unroll 4
        for (int c = 0; c < 128; ++c) s += tile[r][c] * av[c];
        ((tid < 64) ? ssrc : sdst)[(bt << 10) + i0 + r] = s;
    }
    {
        int c = tid & 127, hh2 = tid >> 7;
        u16 tmp[32];
#pragma unroll
        for (int j = 0; j < 32; ++j) tmp[j] = f2b(tile[32 * hh2 + j][c]);
        int tc = c >> 4, lr2 = c & 15;
        u16* dst = WhT + (size_t)bt * 131072 + ((i0 >> 5) + hh2) * 4096 + tc * 512 + lr2 * 8;
#pragma unroll
        for (int lg2 = 0; lg2 < 4; ++lg2) *(short8*)(dst + lg2 * 128) = *(const short8*)(tmp + 8 * lg2);
    }
}

// ================ shared attn main-loop macros ================
#define ATTN_PROLOGUE                                                                \
    __shared__ __align__(16) u16 Bbuf[2][8192];                                      \
    __shared__ __align__(16) float Ej[1024];                                         \
    __shared__ __align__(16) float Fj[1024];                                         \
    int bt = blockIdx.x >> 2, i0b = (blockIdx.x & 3) << 8;                           \
    int b = bt >> 4;                                                                 \
    int tid = threadIdx.x, wv = tid >> 6, l = tid & 63;                              \
    int lr = l & 15, lg = l >> 4;                                                    \
    const u16* wbase = WhT + (size_t)bt * 131072;                                    \
    gload_lds16(wbase + (wv << 10) + l * 8,       &Bbuf[0][(wv << 10)]);             \
    gload_lds16(wbase + (wv << 10) + 512 + l * 8, &Bbuf[0][(wv << 10) + 512]);       \
    for (int k = tid; k < 1024; k += 512) {                                          \
        float sdv = sdst[(bt << 10) + k];                                            \
        Ej[k] = __expf(sdv);                                                         \
        Fj[k] = __expf(0.2f * sdv);                                                  \
    }                                                                                \
    int rb = i0b + (wv << 5);                                                        \
    const u32* mbase = bmT + ((size_t)b << 15);                                      \
    u32 mw0 = mbase[rb + lr];                                                        \
    u32 mw1 = mbase[rb + 16 + lr];                                                   \
    u32 mw2 = mbase[1024 + rb + lr];                                                 \
    u32 mw3 = mbase[1024 + rb + 16 + lr];                                            \
    float si0 = ssrc[(bt << 10) + rb + lr];                                          \
    float si1 = ssrc[(bt << 10) + rb + 16 + lr];                                     \
    float Ei0 = __expf(si0), Fi0 = __expf(0.2f * si0);                               \
    float Ei1 = __expf(si1), Fi1 = __expf(0.2f * si1);                               \
    f32x4 acc[2][8];                                                                 \
    _Pragma("unroll")                                                                \
    for (int rt = 0; rt < 2; ++rt)                                                   \
        _Pragma("unroll")                                                            \
        for (int tc = 0; tc < 8; ++tc) acc[rt][tc] = (f32x4){0.f, 0.f, 0.f, 0.f};    \
    f32x4 accd[2];                                                                   \
    accd[0] = (f32x4){0.f, 0.f, 0.f, 0.f};                                           \
    accd[1] = (f32x4){0.f, 0.f, 0.f, 0.f};                                           \
    short8 bone;                                                                     \
    _Pragma("unroll")                                                                \
    for (int e = 0; e < 8; ++e) bone[e] = (short)0x3F80;                             \
    __syncthreads();

#define PHALF(AF, EI, FI, WW)                                                        \
    {                                                                                \
        u32 byt = ((WW) >> (lg << 3)) & 0xFFu;                                       \
        float pA[8] = {fmaxf((EI) * e0.x, (FI) * f0.x), fmaxf((EI) * e0.y, (FI) * f0.y), \
                       fmaxf((EI) * e0.z, (FI) * f0.z), fmaxf((EI) * e0.w, (FI) * f0.w), \
                       fmaxf((EI) * e1.x, (FI) * f1.x), fmaxf((EI) * e1.y, (FI) * f1.y), \
                       fmaxf((EI) * e1.z, (FI) * f1.z), fmaxf((EI) * e1.w, (FI) * f1.w)}; \
        _Pragma("unroll")                                                            \
        for (int q = 0; q < 4; ++q) {                                                \
            u32 m0 = (u32)(-(int)((byt >> (2 * q)) & 1u));                           \
            u32 m1 = (u32)(-(int)((byt >> (2 * q + 1)) & 1u));                       \
            float p0 = __uint_as_float(__float_as_uint(pA[2 * q]) & m0);             \
            float p1 = __uint_as_float(__float_as_uint(pA[2 * q + 1]) & m1);         \
            asm("v_cvt_pk_bf16_f32 %0, %1, %2" : "=v"(AF.u[q]) : "v"(p0), "v"(p1));  \
        }                                                                            \
    }

#define COMPUTE(JC, CUR, JCL, W0, W1)                                                \
    {                                                                                \
        short8 bfr[8];                                                               \
        _Pragma("unroll")                                                            \
        for (int tc = 0; tc < 8; ++tc)                                               \
            bfr[tc] = *(const short8*)(&Bbuf[CUR][(JCL) * 4096 + tc * 512 + l * 8]); \
        const float* ejp = Ej + ((JC) << 5) + (lg << 3);                             \
        const float* fjp = Fj + ((JC) << 5) + (lg << 3);                             \
        float4 e0 = *(const float4*)ejp, e1 = *(const float4*)(ejp + 4);             \
        float4 f0 = *(const float4*)fjp, f1 = *(const float4*)(fjp + 4);             \
        AFu af0, af1;                                                                \
        PHALF(af0, Ei0, Fi0, W0)                                                     \
        PHALF(af1, Ei1, Fi1, W1)                                                     \
        _Pragma("unroll")                                                            \
        for (int tc = 0; tc < 8; ++tc) {                                             \
            acc[0][tc] = __builtin_amdgcn_mfma_f32_16x16x32_bf16(af0.s, bfr[tc], acc[0][tc], 0, 0, 0); \
            acc[1][tc] = __builtin_amdgcn_mfma_f32_16x16x32_bf16(af1.s, bfr[tc], acc[1][tc], 0, 0, 0); \
        }                                                                            \
        accd[0] = __builtin_amdgcn_mfma_f32_16x16x32_bf16(af0.s, bone, accd[0], 0, 0, 0); \
        accd[1] = __builtin_amdgcn_mfma_f32_16x16x32_bf16(af1.s, bone, accd[1], 0, 0, 0); \
    }

#define ATTN_MAIN_LOOP                                                               \
    for (int c = 0; c < 16; ++c) {                                                   \
        int cur = c & 1;                                                             \
        if (c < 15) {                                                                \
            gload_lds16(wbase + (c + 1) * 8192 + (wv << 10) + l * 8,       &Bbuf[cur ^ 1][(wv << 10)]);       \
            gload_lds16(wbase + (c + 1) * 8192 + (wv << 10) + 512 + l * 8, &Bbuf[cur ^ 1][(wv << 10) + 512]); \
        }                                                                            \
        u32 nw0 = 0, nw1 = 0, nw2 = 0, nw3 = 0;                                      \
        if (c < 15) {                                                                \
            const u32* mp = mbase + ((2 * c + 2) << 10);                             \
            nw0 = mp[rb + lr];        nw1 = mp[rb + 16 + lr];                        \
            nw2 = mp[1024 + rb + lr]; nw3 = mp[1024 + rb + 16 + lr];                 \
        }                                                                            \
        COMPUTE(2 * c,     cur, 0, mw0, mw1)                                         \
        COMPUTE(2 * c + 1, cur, 1, mw2, mw3)                                         \
        mw0 = nw0; mw1 = nw1; mw2 = nw2; mw3 = nw3;                                  \
        __syncthreads();                                                             \
    }

// ---------------- attn layer 1: h out (A-fragment-linear). No min-waves constraint:
// allocator free to settle low (round-11 showed 84 is achievable); no cap -> no spill. ----------------
__global__ __launch_bounds__(512) void k_attnH(const u16* __restrict__ WhT, const float* __restrict__ ssrc,
                                               const float* __restrict__ sdst, const u32* __restrict__ bmT,
                                               u16* __restrict__ hout) {
    ATTN_PROLOGUE
    ATTN_MAIN_LOOP

    // round-11 epilogue: two passes, 8KB wave-private tiles
    char* hb = (char*)(&Bbuf[0][0]) + ((wv & 3) << 13);
    for (int pass = 0; pass < 2; ++pass) {
        if ((wv >> 2) == pass) {
#pragma unroll
            for (int rt = 0; rt < 2; ++rt) {
                float inv[4];
#pragma unroll
                for (int r = 0; r < 4; ++r) inv[r] = 1.f / accd[rt][r];
#pragma unroll
                for (int tc = 0; tc < 8; ++tc)
#pragma unroll
                    for (int r = 0; r < 4; ++r) {
                        float v = acc[rt][tc][r] * inv[r];
                        v = v > 0.f ? v : (__expf(v) - 1.f);
                        v = v > 0.f ? v : (__expf(v) - 1.f);
                        int row = (rt << 4) + (lg << 2) + r;
                        int col = (tc << 4) + lr;
                        *(u16*)(hb + (row << 8) + ((col << 1) ^ ((row & 7) << 4))) = f2b(v);
                    }
            }
            asm volatile("s_waitcnt lgkmcnt(0)" ::: "memory");
            __builtin_amdgcn_sched_barrier(0);
            int rtile0 = rb >> 4;
            u16* dstb = hout + (size_t)bt * 131072;
#pragma unroll
            for (int rt = 0; rt < 2; ++rt)
#pragma unroll
                for (int ch = 0; ch < 4; ++ch) {
                    int row = (rt << 4) + lr;
                    int colb = (ch << 5) + (lg << 3);
                    short8 v = *(const short8*)(hb + (row << 8) + ((colb << 1) ^ ((row & 7) << 4)));
                    *(short8*)(dstb + (size_t)(rtile0 + rt) * 2048 + ch * 512 + l * 8) = v;
                }
        }
        __syncthreads();
    }
}

// ---------------- attn layer 2: fused Gx = elu2(h) @ W_ih^T + bias ----------------
__global__ __launch_bounds__(512, 2) void k_attnG(const u16* __restrict__ WhT, const float* __restrict__ ssrc,
                                                  const float* __restrict__ sdst, const u32* __restrict__ bmT,
                                                  const u16* __restrict__ WihB, const float* __restrict__ bsum,
                                                  u16* __restrict__ Gx) {
    ATTN_PROLOGUE
    ATTN_MAIN_LOOP

    int t = bt & 15;
    char* hb = (char*)(&Bbuf[0][0]) + (wv << 12);

#define EPI_STORE(RT)                                                                 \
    {                                                                                 \
        float inv[4];                                                                 \
        _Pragma("unroll")                                                             \
        for (int r = 0; r < 4; ++r) inv[r] = 1.f / accd[RT][r];                       \
        _Pragma("unroll")                                                             \
        for (int tc = 0; tc < 8; ++tc)                                                \
            _Pragma("unroll")                                                         \
            for (int r = 0; r < 4; ++r) {                                             \
                float v = acc[RT][tc][r] * inv[r];                                    \
                v = v > 0.f ? v : (__expf(v) - 1.f);                                  \
                v = v > 0.f ? v : (__expf(v) - 1.f);                                  \
                int row = (lg << 2) + r;                                              \
                int col = (tc << 4) + lr;                                             \
                *(u16*)(hb + (row << 8) + ((col << 1) ^ ((row & 7) << 4))) = f2b(v);  \
            }                                                                         \
        asm volatile("s_waitcnt lgkmcnt(0)" ::: "memory");                            \
        __builtin_amdgcn_sched_barrier(0);                                            \
    }

#define EPI_OUT_GX(RT)                                                                \
    {                                                                                 \
        int node = i0b + (wv << 5) + ((RT) << 4);                                     \
        int grpx = (b << 6) + (node >> 4);                                            \
        u16* gdst = Gx + (size_t)t * 1048576 + (size_t)grpx * 4096 + l * 8;           \
        _Pragma("unroll")                                                             \
        for (int half = 0; half < 2; ++half) {                                        \
            f32x4 accg[8];                                                            \
            _Pragma("unroll")                                                         \
            for (int tq = 0; tq < 8; ++tq) accg[tq] = (f32x4){0.f, 0.f, 0.f, 0.f};    \
            _Pragma("unroll")                                                         \
            for (int ch = 0; ch < 4; ++ch) {                                          \
                short8 af2 = *(const short8*)(hb + (lr << 8) + (((ch << 6) + (lg << 4)) ^ ((lr & 7) << 4))); \
                _Pragma("unroll")                                                     \
                for (int tq = 0; tq < 8; ++tq) {                                      \
                    int tc = (half << 3) + tq;                                        \
                    short8 bf = *(const short8*)(WihB + ((16 * tc + lr) << 7) + (ch << 5) + 8 * lg); \
                    accg[tq] = __builtin_amdgcn_mfma_f32_16x16x32_bf16(af2, bf, accg[tq], 0, 0, 0); \
                }                                                                     \
            }                                                                         \
            _Pragma("unroll")                                                         \
            for (int qq = 0; qq < 4; ++qq) {                                          \
                int tc0 = (half << 3) + 2 * qq;                                       \
                short8 v;                                                             \
                _Pragma("unroll")                                                     \
                for (int r = 0; r < 4; ++r) {                                         \
                    v[r]     = (short)f2b(accg[2 * qq][r]     + bsum[(tc0 << 4) + lr]); \
                    v[4 + r] = (short)f2b(accg[2 * qq + 1][r] + bsum[((tc0 + 1) << 4) + lr]); \
                }                                                                     \
                *(short8*)(gdst + ((half << 2) + qq) * 512) = v;                      \
            }                                                                         \
        }                                                                             \
    }

    EPI_STORE(0)
    EPI_OUT_GX(0)
    asm volatile("s_waitcnt lgkmcnt(0)" ::: "memory");   // rt0 tile reads done before overwrite
    __builtin_amdgcn_sched_barrier(0);
    EPI_STORE(1)
    EPI_OUT_GX(1)

#undef EPI_STORE
#undef EPI_OUT_GX
}

#undef ATTN_PROLOGUE
#undef ATTN_MAIN_LOOP
#undef PHALF
#undef COMPUTE

// ---------------- LSTM recurrence: 4 waves/block, wave w owns gate-tiles {w,w+4,w+8,w+12}
// (= i/f/g/o for hidden cols [16w,16w+16)); h exchanged via LDS; fused MLP on wave 0 ----------------
__global__ __launch_bounds__(256, 1) void k_lstm(const u16* __restrict__ Gx, const u16* __restrict__ WhhB,
                                                 const float* __restrict__ Wo1, const float* __restrict__ bo1,
                                                 const float* __restrict__ Wo2, const float* __restrict__ bo2,
                                                 float* __restrict__ out) {
    __shared__ u16 hls[16 * 72];
    __shared__ float hf[16 * 65];
    __shared__ float wo1[64 * 32];
    __shared__ float wo2[32];
    int grp = blockIdx.x;
    int m0 = grp << 4;
    int tid = threadIdx.x, wv = tid >> 6, l = tid & 63;
    int lr = l & 15, lg = l >> 4;
    for (int k = tid; k < 64 * 32; k += 256) wo1[k] = Wo1[k];
    if (tid < 32) wo2[tid] = Wo2[tid];
    for (int k = tid; k < 16 * 72; k += 256) hls[k] = 0;
    short8 bh[4][2];
#pragma unroll
    for (int tq = 0; tq < 4; ++tq)
#pragma unroll
        for (int ch = 0; ch < 2; ++ch)
            bh[tq][ch] = *(const short8*)(WhhB + ((16 * (wv + 4 * tq) + lr) << 6) + 32 * ch + 8 * lg);
    float cst[4], hreg[4];
#pragma unroll
    for (int r = 0; r < 4; ++r) { cst[r] = 0.f; hreg[r] = 0.f; }
    int sub = wv & 1;
    // Gx fragments for this wave: q = (wv>>1) + 2*tq
    const u16* gp = Gx + ((size_t)grp << 12) + ((size_t)(wv >> 1) << 9) + l * 8;
    short8 gx0[4], gx1[4];
#pragma unroll
    for (int tq = 0; tq < 4; ++tq) gx0[tq] = *(const short8*)(gp + tq * 1024);
    __syncthreads();
#pragma unroll
    for (int t = 0; t < TT; ++t) {
        if (t < 15) {     // prefetch next step's fragments
#pragma unroll
            for (int tq = 0; tq < 4; ++tq) {
                short8 v = *(const short8*)(gp + (size_t)(t + 1) * 1048576 + tq * 1024);
                if (t & 1) gx0[tq] = v; else gx1[tq] = v;
            }
        }
        f32x4 acc[4];
#pragma unroll
        for (int tq = 0; tq < 4; ++tq) {
            short8 v = (t & 1) ? gx1[tq] : gx0[tq];
#pragma unroll
            for (int r = 0; r < 4; ++r)
                acc[tq][r] = b2f((u16)v[(sub << 2) + r]);
        }
#pragma unroll
        for (int ch = 0; ch < 2; ++ch) {
            short8 af = *(const short8*)(hls + lr * 72 + 32 * ch + 8 * lg);
#pragma unroll
            for (int tq = 0; tq < 4; ++tq)
                acc[tq] = __builtin_amdgcn_mfma_f32_16x16x32_bf16(af, bh[tq][ch], acc[tq], 0, 0, 0);
        }
#pragma unroll
        for (int r = 0; r < 4; ++r) {
            float iv = fsig(acc[0][r]);
            float fv = fsig(acc[1][r]);
            float gv = ftanh(acc[2][r]);
            float ov = fsig(acc[3][r]);
            float cn = __builtin_fmaf(fv, cst[r], iv * gv);
            cst[r] = cn;
            hreg[r] = ov * ftanh(cn);
        }
        __syncthreads();     // all waves done reading hls
#pragma unroll
        for (int r = 0; r < 4; ++r)
            hls[(4 * lg + r) * 72 + 16 * wv + lr] = f2b(hreg[r]);
        __syncthreads();     // h ready for next step
    }
#pragma unroll
    for (int r = 0; r < 4; ++r)
        hf[(4 * lg + r) * 65 + 16 * wv + lr] = hreg[r];
    __syncthreads();
    if (wv == 0) {
        int r = lr, p = lg;
        float hid[8];
#pragma unroll
        for (int q = 0; q < 8; ++q) hid[q] = bo1[8 * p + q];
        for (int j = 0; j < 64; ++j) {
            float hv = hf[r * 65 + j];
#pragma unroll
            for (int q = 0; q < 8; ++q) hid[q] += hv * wo1[j * 32 + 8 * p + q];
        }
        float po = 0.f;
#pragma unroll
        for (int q = 0; q < 8; ++q) po += fmaxf(hid[q], 0.f) * wo2[8 * p + q];
        po += __shfl_xor(po, 16);
        po += __shfl_xor(po, 32);
        if (p == 0) out[m0 + r] = po + bo2[0];
    }
}

extern "C" void kernel_launch(void* const* d_in, const int* in_sizes, int n_in,
                              void* d_out, int out_size, void* d_ws, size_t ws_size,
                              hipStream_t stream) {
    const float* x    = (const float*)d_in[0];
    const int*   adj  = (const int*)d_in[1];
    const float* W1   = (const float*)d_in[2];
    const float* a1   = (const float*)d_in[3];
    const float* W2   = (const float*)d_in[4];
    const float* a2   = (const float*)d_in[5];
    const float* W_ih = (const float*)d_in[6];
    const float* W_hh = (const float*)d_in[7];
    const float* b_ih = (const float*)d_in[8];
    const float* b_hh = (const float*)d_in[9];
    const float* Wo1  = (const float*)d_in[10];
    const float* bo1  = (const float*)d_in[11];
    const float* Wo2  = (const float*)d_in[12];
    const float* bo2  = (const float*)d_in[13];
    float* out = (float*)d_out;

    char* w = (char*)d_ws;
    const size_t SLOT = (size_t)8388608 * sizeof(u16);   // 16.78 MB
    u16* A  = (u16*)w;
    u16* Bf = (u16*)(w + SLOT);
    u16* C  = (u16*)(w + 2 * SLOT);
    char* sm = w + 3 * SLOT;
    float* s1s = (float*)sm;
    float* s1d = s1s + 65536;
    float* s2s = s1d + 65536;
    float* s2d = s2s + 65536;
    u32* BM  = (u32*)(s2d + 65536);      // 131072 words (512 KB), transposed layout
    u16* W1T = (u16*)(BM + 131072);      // 4096
    u16* W2T = W1T + 4096;               // 16384
    u16* WihB = W2T + 16384;             // 32768
    u16* WhhB = WihB + 32768;            // 16384
    float* BS = (float*)(WhhB + 16384);  // 256
    u16* Gx = Bf;                        // Bf dead after projB; Gx spans Bf..C (33.55 MB)

    k_pre<<<64, 256, 0, stream>>>(W1, W2, W_ih, W_hh, b_ih, b_hh, W1T, W2T, WihB, WhhB, BS);
    k_mask<<<1024, 256, 0, stream>>>(adj, BM);
    k_projA<<<1024, 256, 0, stream>>>(x, W1T, a1, A, s1s, s1d);
    k_attnH<<<256, 512, 0, stream>>>(A, s1s, s1d, BM, Bf);
    k_projB<<<1024, 256, 0, stream>>>(Bf, W2T, a2, C, s2s, s2d);
    k_attnG<<<256, 512, 0, stream>>>(C, s2s, s2d, BM, WihB, BS, Gx);
    k_lstm<<<256, 256, 0, stream>>>(Gx, WhhB, Wo1, bo1, Wo2, bo2, out);
}

// Round 17
// 166.672 us; speedup vs baseline: 2.3104x; 1.0051x over previous
//
#include <hip/hip_runtime.h>
#include <hip/hip_bf16.h>
#include <math.h>

#define BB 4
#define NN 1024
#define TT 16
#define FIN 32
#define HH 128
#define LH 64
#define MLPH 32

typedef __attribute__((ext_vector_type(8))) short short8;
typedef __attribute__((ext_vector_type(4))) float f32x4;
typedef unsigned short u16;
typedef unsigned int u32;

union AFu { u32 u[4]; short8 s; };

__device__ __forceinline__ u16 f2b(float f) {
    union { float f; u32 u; } v; v.f = f;
    u32 u = v.u;
    return (u16)((u + 0x7FFFu + ((u >> 16) & 1u)) >> 16);
}
__device__ __forceinline__ float b2f(u16 h) {
    union { u32 u; float f; } v; v.u = ((u32)h) << 16;
    return v.f;
}
__device__ __forceinline__ float frcp(float x) {
    float r; asm("v_rcp_f32 %0, %1" : "=v"(r) : "v"(x)); return r;
}
__device__ __forceinline__ float fsig(float x) {          // 1/(1+e^-x)
    return frcp(1.f + __expf(-x));
}
__device__ __forceinline__ float ftanh(float x) {         // 2*sig(2x)-1
    return __builtin_fmaf(2.f, frcp(1.f + __expf(-2.f * x)), -1.f);
}
__device__ __forceinline__ void gload_lds16(const void* g, void* l) {
    __builtin_amdgcn_global_load_lds((const __attribute__((address_space(1))) unsigned int*)g,
                                     (__attribute__((address_space(3))) unsigned int*)l, 16, 0, 0);
}

// ---------------- precompute (parallel): bf16 weight layouts + fused bias ----------------
__global__ __launch_bounds__(256) void k_pre(const float* __restrict__ W1, const float* __restrict__ W2,
                      const float* __restrict__ W_ih, const float* __restrict__ W_hh,
                      const float* __restrict__ b_ih, const float* __restrict__ b_hh,
                      u16* W1T, u16* W2T, u16* WihB, u16* WhhB, float* bsum) {
    int gi = blockIdx.x * 256 + threadIdx.x;     // 64 blocks -> 16384 threads
    for (int i = gi; i < 128 * 32; i += 16384) { int c = i >> 5, k = i & 31; W1T[i] = f2b(W1[k * 128 + c]); }
    for (int i = gi; i < 128 * 128; i += 16384) { int c = i >> 7, k = i & 127; W2T[i] = f2b(W2[k * 128 + c]); }
    for (int i = gi; i < 256 * 128; i += 16384) WihB[i] = f2b(W_ih[i]);
    for (int i = gi; i < 256 * 64; i += 16384) WhhB[i] = f2b(W_hh[i]);
    if (gi < 256) bsum[gi] = b_ih[gi] + b_hh[gi];
}

// ---------------- adjacency -> bitmask, TRANSPOSED: bmT[b][wd(32)][row(1024)] u32 ----------------
__global__ __launch_bounds__(256) void k_mask(const int* __restrict__ adj, u32* __restrict__ bmT) {
    int gw = (blockIdx.x * 256 + threadIdx.x) >> 6;  // 4096 waves
    int lane = threadIdx.x & 63;
    int base = gw << 4;                              // 16 consecutive words per wave
#pragma unroll 4
    for (int it = 0; it < 16; ++it) {
        int u = base + it;
        unsigned long long m = __ballot(adj[((size_t)u << 6) + lane] > 0);
        if (lane == 0) {
            int g = u & 15;          // 64-j group -> words 2g, 2g+1
            int bi = u >> 4;
            int b = bi >> 10, i = bi & 1023;
            bmT[(((b << 5) + 2 * g) << 10) + i]     = (u32)m;
            bmT[(((b << 5) + 2 * g + 1) << 10) + i] = (u32)(m >> 32);
        }
    }
}

// WhT fragment-linear layout: 8KB per jc: [bt][jc(32)][tc(8)][lane][8e]

// ---------------- GAT layer-1 projection (MFMA): x -> Wh1 frag-linear + s vectors ----------------
__global__ __launch_bounds__(256) void k_projA(const float* __restrict__ x, const u16* __restrict__ W1T,
                                               const float* __restrict__ a1,
                                               u16* __restrict__ WhT, float* __restrict__ ssrc,
                                               float* __restrict__ sdst) {
    __shared__ float tile[64][132];
    __shared__ float sA[256];
    int bt = blockIdx.x >> 4, i0 = (blockIdx.x & 15) << 6;
    int b = bt >> 4, t = bt & 15;
    int tid = threadIdx.x, w = tid >> 6, l = tid & 63;
    int lr = l & 15, lg = l >> 4;
    sA[tid] = a1[tid];
    int i = i0 + 16 * w + lr;
    const float* xp = x + ((size_t)((b << 10) + i) * TT + t) * FIN + 8 * lg;
    float4 x0 = *(const float4*)xp;
    float4 x1 = *(const float4*)(xp + 4);
    short8 af;
    af[0] = (short)f2b(x0.x); af[1] = (short)f2b(x0.y); af[2] = (short)f2b(x0.z); af[3] = (short)f2b(x0.w);
    af[4] = (short)f2b(x1.x); af[5] = (short)f2b(x1.y); af[6] = (short)f2b(x1.z); af[7] = (short)f2b(x1.w);
    f32x4 zz = {0.f, 0.f, 0.f, 0.f};
#pragma unroll
    for (int tc = 0; tc < 8; ++tc) {
        short8 bf = *(const short8*)(W1T + ((16 * tc + lr) << 5) + 8 * lg);
        f32x4 d = __builtin_amdgcn_mfma_f32_16x16x32_bf16(af, bf, zz, 0, 0, 0);
#pragma unroll
        for (int r = 0; r < 4; ++r) tile[16 * w + 4 * lg + r][16 * tc + lr] = d[r];
    }
    __syncthreads();
    if (tid < 128) {
        int r = tid & 63;
        const float* av = sA + ((tid < 64) ? 0 : 128);
        float s = 0.f;
#pragma unroll 4
        for (int c = 0; c < 128; ++c) s += tile[r][c] * av[c];
        ((tid < 64) ? ssrc : sdst)[(bt << 10) + i0 + r] = s;
    }
    {   // write frag-linear: jc = (i0>>5)+hh2, 32 rows each
        int c = tid & 127, hh2 = tid >> 7;
        u16 tmp[32];
#pragma unroll
        for (int j = 0; j < 32; ++j) tmp[j] = f2b(tile[32 * hh2 + j][c]);
        int tc = c >> 4, lr2 = c & 15;
        u16* dst = WhT + (size_t)bt * 131072 + ((i0 >> 5) + hh2) * 4096 + tc * 512 + lr2 * 8;
#pragma unroll
        for (int lg2 = 0; lg2 < 4; ++lg2) *(short8*)(dst + lg2 * 128) = *(const short8*)(tmp + 8 * lg2);
    }
}

// ---------------- GAT layer-2 projection (MFMA): h1 frag-linear -> Wh2 frag-linear + s vectors ----------------
__global__ __launch_bounds__(256) void k_projB(const u16* __restrict__ h1, const u16* __restrict__ W2T,
                                               const float* __restrict__ a2,
                                               u16* __restrict__ WhT, float* __restrict__ ssrc,
                                               float* __restrict__ sdst) {
    __shared__ float tile[64][132];
    __shared__ float sA[256];
    int bt = blockIdx.x >> 4, i0 = (blockIdx.x & 15) << 6;
    int tid = threadIdx.x, w = tid >> 6, l = tid & 63;
    int lr = l & 15, lg = l >> 4;
    sA[tid] = a2[tid];
    const u16* ap = h1 + (size_t)bt * 131072 + ((i0 >> 4) + w) * 2048 + l * 8;
    f32x4 acc[8];
#pragma unroll
    for (int tc = 0; tc < 8; ++tc) acc[tc] = (f32x4){0.f, 0.f, 0.f, 0.f};
#pragma unroll
    for (int ch = 0; ch < 4; ++ch) {
        short8 af = *(const short8*)(ap + ch * 512);
#pragma unroll
        for (int tc = 0; tc < 8; ++tc) {
            short8 bf = *(const short8*)(W2T + ((16 * tc + lr) << 7) + 32 * ch + 8 * lg);
            acc[tc] = __builtin_amdgcn_mfma_f32_16x16x32_bf16(af, bf, acc[tc], 0, 0, 0);
        }
    }
#pragma unroll
    for (int tc = 0; tc < 8; ++tc)
#pragma unroll
        for (int r = 0; r < 4; ++r) tile[16 * w + 4 * lg + r][16 * tc + lr] = acc[tc][r];
    __syncthreads();
    if (tid < 128) {
        int r = tid & 63;
        const float* av = sA + ((tid < 64) ? 0 : 128);
        float s = 0.f;
#pragma unroll 4
        for (int c = 0; c < 128; ++c) s += tile[r][c] * av[c];
        ((tid < 64) ? ssrc : sdst)[(bt << 10) + i0 + r] = s;
    }
    {
        int c = tid & 127, hh2 = tid >> 7;
        u16 tmp[32];
#pragma unroll
        for (int j = 0; j < 32; ++j) tmp[j] = f2b(tile[32 * hh2 + j][c]);
        int tc = c >> 4, lr2 = c & 15;
        u16* dst = WhT + (size_t)bt * 131072 + ((i0 >> 5) + hh2) * 4096 + tc * 512 + lr2 * 8;
#pragma unroll
        for (int lg2 = 0; lg2 < 4; ++lg2) *(short8*)(dst + lg2 * 128) = *(const short8*)(tmp + 8 * lg2);
    }
}

// ================ shared attn main-loop macros ================
#define ATTN_PROLOGUE                                                                \
    __shared__ __align__(16) u16 Bbuf[2][8192];                                      \
    __shared__ __align__(16) float Ej[1024];                                         \
    __shared__ __align__(16) float Fj[1024];                                         \
    int bt = blockIdx.x >> 2, i0b = (blockIdx.x & 3) << 8;                           \
    int b = bt >> 4;                                                                 \
    int tid = threadIdx.x, wv = tid >> 6, l = tid & 63;                              \
    int lr = l & 15, lg = l >> 4;                                                    \
    const u16* wbase = WhT + (size_t)bt * 131072;                                    \
    gload_lds16(wbase + (wv << 10) + l * 8,       &Bbuf[0][(wv << 10)]);             \
    gload_lds16(wbase + (wv << 10) + 512 + l * 8, &Bbuf[0][(wv << 10) + 512]);       \
    for (int k = tid; k < 1024; k += 512) {                                          \
        float sdv = sdst[(bt << 10) + k];                                            \
        Ej[k] = __expf(sdv);                                                         \
        Fj[k] = __expf(0.2f * sdv);                                                  \
    }                                                                                \
    int rb = i0b + (wv << 5);                                                        \
    const u32* mbase = bmT + ((size_t)b << 15);                                      \
    u32 mw0 = mbase[rb + lr];                                                        \
    u32 mw1 = mbase[rb + 16 + lr];                                                   \
    u32 mw2 = mbase[1024 + rb + lr];                                                 \
    u32 mw3 = mbase[1024 + rb + 16 + lr];                                            \
    float si0 = ssrc[(bt << 10) + rb + lr];                                          \
    float si1 = ssrc[(bt << 10) + rb + 16 + lr];                                     \
    float Ei0 = __expf(si0), Fi0 = __expf(0.2f * si0);                               \
    float Ei1 = __expf(si1), Fi1 = __expf(0.2f * si1);                               \
    f32x4 acc[2][8];                                                                 \
    _Pragma("unroll")                                                                \
    for (int rt = 0; rt < 2; ++rt)                                                   \
        _Pragma("unroll")                                                            \
        for (int tc = 0; tc < 8; ++tc) acc[rt][tc] = (f32x4){0.f, 0.f, 0.f, 0.f};    \
    f32x4 accd[2];                                                                   \
    accd[0] = (f32x4){0.f, 0.f, 0.f, 0.f};                                           \
    accd[1] = (f32x4){0.f, 0.f, 0.f, 0.f};                                           \
    short8 bone;                                                                     \
    _Pragma("unroll")                                                                \
    for (int e = 0; e < 8; ++e) bone[e] = (short)0x3F80;                             \
    __syncthreads();

#define PHALF(AF, EI, FI, WW)                                                        \
    {                                                                                \
        u32 byt = ((WW) >> (lg << 3)) & 0xFFu;                                       \
        float pA[8] = {fmaxf((EI) * e0.x, (FI) * f0.x), fmaxf((EI) * e0.y, (FI) * f0.y), \
                       fmaxf((EI) * e0.z, (FI) * f0.z), fmaxf((EI) * e0.w, (FI) * f0.w), \
                       fmaxf((EI) * e1.x, (FI) * f1.x), fmaxf((EI) * e1.y, (FI) * f1.y), \
                       fmaxf((EI) * e1.z, (FI) * f1.z), fmaxf((EI) * e1.w, (FI) * f1.w)}; \
        _Pragma("unroll")                                                            \
        for (int q = 0; q < 4; ++q) {                                                \
            u32 m0 = (u32)(-(int)((byt >> (2 * q)) & 1u));                           \
            u32 m1 = (u32)(-(int)((byt >> (2 * q + 1)) & 1u));                       \
            float p0 = __uint_as_float(__float_as_uint(pA[2 * q]) & m0);             \
            float p1 = __uint_as_float(__float_as_uint(pA[2 * q + 1]) & m1);         \
            asm("v_cvt_pk_bf16_f32 %0, %1, %2" : "=v"(AF.u[q]) : "v"(p0), "v"(p1));  \
        }                                                                            \
    }

// streamed B-fragments: one ds_read feeding 2 MFMAs at a time -> peak live bfr = 1
// (vs 8 batched = 32 VGPR). Goal: allocator lands <=85 VGPR -> 6 waves/SIMD.
#define COMPUTE(JC, CUR, JCL, W0, W1)                                                \
    {                                                                                \
        const float* ejp = Ej + ((JC) << 5) + (lg << 3);                             \
        const float* fjp = Fj + ((JC) << 5) + (lg << 3);                             \
        float4 e0 = *(const float4*)ejp, e1 = *(const float4*)(ejp + 4);             \
        float4 f0 = *(const float4*)fjp, f1 = *(const float4*)(fjp + 4);             \
        AFu af0, af1;                                                                \
        PHALF(af0, Ei0, Fi0, W0)                                                     \
        PHALF(af1, Ei1, Fi1, W1)                                                     \
        _Pragma("unroll")                                                            \
        for (int tc = 0; tc < 8; ++tc) {                                             \
            short8 bfr = *(const short8*)(&Bbuf[CUR][(JCL) * 4096 + tc * 512 + l * 8]); \
            acc[0][tc] = __builtin_amdgcn_mfma_f32_16x16x32_bf16(af0.s, bfr, acc[0][tc], 0, 0, 0); \
            acc[1][tc] = __builtin_amdgcn_mfma_f32_16x16x32_bf16(af1.s, bfr, acc[1][tc], 0, 0, 0); \
        }                                                                            \
        accd[0] = __builtin_amdgcn_mfma_f32_16x16x32_bf16(af0.s, bone, accd[0], 0, 0, 0); \
        accd[1] = __builtin_amdgcn_mfma_f32_16x16x32_bf16(af1.s, bone, accd[1], 0, 0, 0); \
    }

#define ATTN_MAIN_LOOP                                                               \
    for (int c = 0; c < 16; ++c) {                                                   \
        int cur = c & 1;                                                             \
        if (c < 15) {                                                                \
            gload_lds16(wbase + (c + 1) * 8192 + (wv << 10) + l * 8,       &Bbuf[cur ^ 1][(wv << 10)]);       \
            gload_lds16(wbase + (c + 1) * 8192 + (wv << 10) + 512 + l * 8, &Bbuf[cur ^ 1][(wv << 10) + 512]); \
        }                                                                            \
        u32 nw0 = 0, nw1 = 0, nw2 = 0, nw3 = 0;                                      \
        if (c < 15) {                                                                \
            const u32* mp = mbase + ((2 * c + 2) << 10);                             \
            nw0 = mp[rb + lr];        nw1 = mp[rb + 16 + lr];                        \
            nw2 = mp[1024 + rb + lr]; nw3 = mp[1024 + rb + 16 + lr];                 \
        }                                                                            \
        COMPUTE(2 * c,     cur, 0, mw0, mw1)                                         \
        COMPUTE(2 * c + 1, cur, 1, mw2, mw3)                                         \
        mw0 = nw0; mw1 = nw1; mw2 = nw2; mw3 = nw3;                                  \
        __syncthreads();                                                             \
    }

// ---------------- attn layer 1: h out (A-fragment-linear) ----------------
__global__ __launch_bounds__(512) void k_attnH(const u16* __restrict__ WhT, const float* __restrict__ ssrc,
                                               const float* __restrict__ sdst, const u32* __restrict__ bmT,
                                               u16* __restrict__ hout) {
    ATTN_PROLOGUE
    ATTN_MAIN_LOOP

    // round-11 epilogue: two passes, 8KB wave-private tiles
    char* hb = (char*)(&Bbuf[0][0]) + ((wv & 3) << 13);
    for (int pass = 0; pass < 2; ++pass) {
        if ((wv >> 2) == pass) {
#pragma unroll
            for (int rt = 0; rt < 2; ++rt) {
                float inv[4];
#pragma unroll
                for (int r = 0; r < 4; ++r) inv[r] = 1.f / accd[rt][r];
#pragma unroll
                for (int tc = 0; tc < 8; ++tc)
#pragma unroll
                    for (int r = 0; r < 4; ++r) {
                        float v = acc[rt][tc][r] * inv[r];
                        v = v > 0.f ? v : (__expf(v) - 1.f);
                        v = v > 0.f ? v : (__expf(v) - 1.f);
                        int row = (rt << 4) + (lg << 2) + r;
                        int col = (tc << 4) + lr;
                        *(u16*)(hb + (row << 8) + ((col << 1) ^ ((row & 7) << 4))) = f2b(v);
                    }
            }
            asm volatile("s_waitcnt lgkmcnt(0)" ::: "memory");
            __builtin_amdgcn_sched_barrier(0);
            int rtile0 = rb >> 4;
            u16* dstb = hout + (size_t)bt * 131072;
#pragma unroll
            for (int rt = 0; rt < 2; ++rt)
#pragma unroll
                for (int ch = 0; ch < 4; ++ch) {
                    int row = (rt << 4) + lr;
                    int colb = (ch << 5) + (lg << 3);
                    short8 v = *(const short8*)(hb + (row << 8) + ((colb << 1) ^ ((row & 7) << 4)));
                    *(short8*)(dstb + (size_t)(rtile0 + rt) * 2048 + ch * 512 + l * 8) = v;
                }
        }
        __syncthreads();
    }
}

// ---------------- attn layer 2: fused Gx = elu2(h) @ W_ih^T + bias ----------------
__global__ __launch_bounds__(512, 2) void k_attnG(const u16* __restrict__ WhT, const float* __restrict__ ssrc,
                                                  const float* __restrict__ sdst, const u32* __restrict__ bmT,
                                                  const u16* __restrict__ WihB, const float* __restrict__ bsum,
                                                  u16* __restrict__ Gx) {
    ATTN_PROLOGUE
    ATTN_MAIN_LOOP

    int t = bt & 15;
    char* hb = (char*)(&Bbuf[0][0]) + (wv << 12);

#define EPI_STORE(RT)                                                                 \
    {                                                                                 \
        float inv[4];                                                                 \
        _Pragma("unroll")                                                             \
        for (int r = 0; r < 4; ++r) inv[r] = 1.f / accd[RT][r];                       \
        _Pragma("unroll")                                                             \
        for (int tc = 0; tc < 8; ++tc)                                                \
            _Pragma("unroll")                                                         \
            for (int r = 0; r < 4; ++r) {                                             \
                float v = acc[RT][tc][r] * inv[r];                                    \
                v = v > 0.f ? v : (__expf(v) - 1.f);                                  \
                v = v > 0.f ? v : (__expf(v) - 1.f);                                  \
                int row = (lg << 2) + r;                                              \
                int col = (tc << 4) + lr;                                             \
                *(u16*)(hb + (row << 8) + ((col << 1) ^ ((row & 7) << 4))) = f2b(v);  \
            }                                                                         \
        asm volatile("s_waitcnt lgkmcnt(0)" ::: "memory");                            \
        __builtin_amdgcn_sched_barrier(0);                                            \
    }

#define EPI_OUT_GX(RT)                                                                \
    {                                                                                 \
        int node = i0b + (wv << 5) + ((RT) << 4);                                     \
        int grpx = (b << 6) + (node >> 4);                                            \
        u16* gdst = Gx + (size_t)t * 1048576 + (size_t)grpx * 4096 + l * 8;           \
        _Pragma("unroll")                                                             \
        for (int half = 0; half < 2; ++half) {                                        \
            f32x4 accg[8];                                                            \
            _Pragma("unroll")                                                         \
            for (int tq = 0; tq < 8; ++tq) accg[tq] = (f32x4){0.f, 0.f, 0.f, 0.f};    \
            _Pragma("unroll")                                                         \
            for (int ch = 0; ch < 4; ++ch) {                                          \
                short8 af2 = *(const short8*)(hb + (lr << 8) + (((ch << 6) + (lg << 4)) ^ ((lr & 7) << 4))); \
                _Pragma("unroll")                                                     \
                for (int tq = 0; tq < 8; ++tq) {                                      \
                    int tc = (half << 3) + tq;                                        \
                    short8 bf = *(const short8*)(WihB + ((16 * tc + lr) << 7) + (ch << 5) + 8 * lg); \
                    accg[tq] = __builtin_amdgcn_mfma_f32_16x16x32_bf16(af2, bf, accg[tq], 0, 0, 0); \
                }                                                                     \
            }                                                                         \
            _Pragma("unroll")                                                         \
            for (int qq = 0; qq < 4; ++qq) {                                          \
                int tc0 = (half << 3) + 2 * qq;                                       \
                short8 v;                                                             \
                _Pragma("unroll")                                                     \
                for (int r = 0; r < 4; ++r) {                                         \
                    v[r]     = (short)f2b(accg[2 * qq][r]     + bsum[(tc0 << 4) + lr]); \
                    v[4 + r] = (short)f2b(accg[2 * qq + 1][r] + bsum[((tc0 + 1) << 4) + lr]); \
                }                                                                     \
                *(short8*)(gdst + ((half << 2) + qq) * 512) = v;                      \
            }                                                                         \
        }                                                                             \
    }

    EPI_STORE(0)
    EPI_OUT_GX(0)
    asm volatile("s_waitcnt lgkmcnt(0)" ::: "memory");   // rt0 tile reads done before overwrite
    __builtin_amdgcn_sched_barrier(0);
    EPI_STORE(1)
    EPI_OUT_GX(1)

#undef EPI_STORE
#undef EPI_OUT_GX
}

#undef ATTN_PROLOGUE
#undef ATTN_MAIN_LOOP
#undef PHALF
#undef COMPUTE

// ---------------- LSTM recurrence: 4 waves/block, wave w owns gate-tiles {w,w+4,w+8,w+12}
// (= i/f/g/o for hidden cols [16w,16w+16)); h exchanged via LDS; fused MLP on wave 0 ----------------
__global__ __launch_bounds__(256, 1) void k_lstm(const u16* __restrict__ Gx, const u16* __restrict__ WhhB,
                                                 const float* __restrict__ Wo1, const float* __restrict__ bo1,
                                                 const float* __restrict__ Wo2, const float* __restrict__ bo2,
                                                 float* __restrict__ out) {
    __shared__ u16 hls[16 * 72];
    __shared__ float hf[16 * 65];
    __shared__ float wo1[64 * 32];
    __shared__ float wo2[32];
    int grp = blockIdx.x;
    int m0 = grp << 4;
    int tid = threadIdx.x, wv = tid >> 6, l = tid & 63;
    int lr = l & 15, lg = l >> 4;
    for (int k = tid; k < 64 * 32; k += 256) wo1[k] = Wo1[k];
    if (tid < 32) wo2[tid] = Wo2[tid];
    for (int k = tid; k < 16 * 72; k += 256) hls[k] = 0;
    short8 bh[4][2];
#pragma unroll
    for (int tq = 0; tq < 4; ++tq)
#pragma unroll
        for (int ch = 0; ch < 2; ++ch)
            bh[tq][ch] = *(const short8*)(WhhB + ((16 * (wv + 4 * tq) + lr) << 6) + 32 * ch + 8 * lg);
    float cst[4], hreg[4];
#pragma unroll
    for (int r = 0; r < 4; ++r) { cst[r] = 0.f; hreg[r] = 0.f; }
    int sub = wv & 1;
    // Gx fragments for this wave: q = (wv>>1) + 2*tq
    const u16* gp = Gx + ((size_t)grp << 12) + ((size_t)(wv >> 1) << 9) + l * 8;
    short8 gx0[4], gx1[4];
#pragma unroll
    for (int tq = 0; tq < 4; ++tq) gx0[tq] = *(const short8*)(gp + tq * 1024);
    __syncthreads();
#pragma unroll
    for (int t = 0; t < TT; ++t) {
        if (t < 15) {     // prefetch next step's fragments
#pragma unroll
            for (int tq = 0; tq < 4; ++tq) {
                short8 v = *(const short8*)(gp + (size_t)(t + 1) * 1048576 + tq * 1024);
                if (t & 1) gx0[tq] = v; else gx1[tq] = v;
            }
        }
        f32x4 acc[4];
#pragma unroll
        for (int tq = 0; tq < 4; ++tq) {
            short8 v = (t & 1) ? gx1[tq] : gx0[tq];
#pragma unroll
            for (int r = 0; r < 4; ++r)
                acc[tq][r] = b2f((u16)v[(sub << 2) + r]);
        }
#pragma unroll
        for (int ch = 0; ch < 2; ++ch) {
            short8 af = *(const short8*)(hls + lr * 72 + 32 * ch + 8 * lg);
#pragma unroll
            for (int tq = 0; tq < 4; ++tq)
                acc[tq] = __builtin_amdgcn_mfma_f32_16x16x32_bf16(af, bh[tq][ch], acc[tq], 0, 0, 0);
        }
#pragma unroll
        for (int r = 0; r < 4; ++r) {
            float iv = fsig(acc[0][r]);
            float fv = fsig(acc[1][r]);
            float gv = ftanh(acc[2][r]);
            float ov = fsig(acc[3][r]);
            float cn = __builtin_fmaf(fv, cst[r], iv * gv);
            cst[r] = cn;
            hreg[r] = ov * ftanh(cn);
        }
        __syncthreads();     // all waves done reading hls
#pragma unroll
        for (int r = 0; r < 4; ++r)
            hls[(4 * lg + r) * 72 + 16 * wv + lr] = f2b(hreg[r]);
        __syncthreads();     // h ready for next step
    }
#pragma unroll
    for (int r = 0; r < 4; ++r)
        hf[(4 * lg + r) * 65 + 16 * wv + lr] = hreg[r];
    __syncthreads();
    if (wv == 0) {
        int r = lr, p = lg;
        float hid[8];
#pragma unroll
        for (int q = 0; q < 8; ++q) hid[q] = bo1[8 * p + q];
        for (int j = 0; j < 64; ++j) {
            float hv = hf[r * 65 + j];
#pragma unroll
            for (int q = 0; q < 8; ++q) hid[q] += hv * wo1[j * 32 + 8 * p + q];
        }
        float po = 0.f;
#pragma unroll
        for (int q = 0; q < 8; ++q) po += fmaxf(hid[q], 0.f) * wo2[8 * p + q];
        po += __shfl_xor(po, 16);
        po += __shfl_xor(po, 32);
        if (p == 0) out[m0 + r] = po + bo2[0];
    }
}

extern "C" void kernel_launch(void* const* d_in, const int* in_sizes, int n_in,
                              void* d_out, int out_size, void* d_ws, size_t ws_size,
                              hipStream_t stream) {
    const float* x    = (const float*)d_in[0];
    const int*   adj  = (const int*)d_in[1];
    const float* W1   = (const float*)d_in[2];
    const float* a1   = (const float*)d_in[3];
    const float* W2   = (const float*)d_in[4];
    const float* a2   = (const float*)d_in[5];
    const float* W_ih = (const float*)d_in[6];
    const float* W_hh = (const float*)d_in[7];
    const float* b_ih = (const float*)d_in[8];
    const float* b_hh = (const float*)d_in[9];
    const float* Wo1  = (const float*)d_in[10];
    const float* bo1  = (const float*)d_in[11];
    const float* Wo2  = (const float*)d_in[12];
    const float* bo2  = (const float*)d_in[13];
    float* out = (float*)d_out;

    char* w = (char*)d_ws;
    const size_t SLOT = (size_t)8388608 * sizeof(u16);   // 16.78 MB
    u16* A  = (u16*)w;
    u16* Bf = (u16*)(w + SLOT);
    u16* C  = (u16*)(w + 2 * SLOT);
    char* sm = w + 3 * SLOT;
    float* s1s = (float*)sm;
    float* s1d = s1s + 65536;
    float* s2s = s1d + 65536;
    float* s2d = s2s + 65536;
    u32* BM  = (u32*)(s2d + 65536);      // 131072 words (512 KB), transposed layout
    u16* W1T = (u16*)(BM + 131072);      // 4096
    u16* W2T = W1T + 4096;               // 16384
    u16* WihB = W2T + 16384;             // 32768
    u16* WhhB = WihB + 32768;            // 16384
    float* BS = (float*)(WhhB + 16384);  // 256
    u16* Gx = Bf;                        // Bf dead after projB; Gx spans Bf..C (33.55 MB)

    k_pre<<<64, 256, 0, stream>>>(W1, W2, W_ih, W_hh, b_ih, b_hh, W1T, W2T, WihB, WhhB, BS);
    k_mask<<<1024, 256, 0, stream>>>(adj, BM);
    k_projA<<<1024, 256, 0, stream>>>(x, W1T, a1, A, s1s, s1d);
    k_attnH<<<256, 512, 0, stream>>>(A, s1s, s1d, BM, Bf);
    k_projB<<<1024, 256, 0, stream>>>(Bf, W2T, a2, C, s2s, s2d);
    k_attnG<<<256, 512, 0, stream>>>(C, s2s, s2d, BM, WihB, BS, Gx);
    k_lstm<<<256, 256, 0, stream>>>(Gx, WhhB, Wo1, bo1, Wo2, bo2, out);
}

// Round 18
// 157.127 us; speedup vs baseline: 2.4507x; 1.0608x over previous
//
#include <hip/hip_runtime.h>
#include <hip/hip_bf16.h>
#include <math.h>

#define BB 4
#define NN 1024
#define TT 16
#define FIN 32
#define HH 128
#define LH 64
#define MLPH 32

typedef __attribute__((ext_vector_type(8))) short short8;
typedef __attribute__((ext_vector_type(4))) short short4v;
typedef __attribute__((ext_vector_type(4))) float f32x4;
typedef unsigned short u16;
typedef unsigned int u32;

union AFu { u32 u[4]; short8 s; };

__device__ __forceinline__ u16 f2b(float f) {
    union { float f; u32 u; } v; v.f = f;
    u32 u = v.u;
    return (u16)((u + 0x7FFFu + ((u >> 16) & 1u)) >> 16);
}
__device__ __forceinline__ float b2f(u16 h) {
    union { u32 u; float f; } v; v.u = ((u32)h) << 16;
    return v.f;
}
__device__ __forceinline__ float frcp(float x) {
    float r; asm("v_rcp_f32 %0, %1" : "=v"(r) : "v"(x)); return r;
}
__device__ __forceinline__ float fsig(float x) {          // 1/(1+e^-x)
    return frcp(1.f + __expf(-x));
}
__device__ __forceinline__ float ftanh(float x) {         // 2*sig(2x)-1
    return __builtin_fmaf(2.f, frcp(1.f + __expf(-2.f * x)), -1.f);
}
__device__ __forceinline__ void gload_lds16(const void* g, void* l) {
    __builtin_amdgcn_global_load_lds((const __attribute__((address_space(1))) unsigned int*)g,
                                     (__attribute__((address_space(3))) unsigned int*)l, 16, 0, 0);
}

// ---------------- precompute (parallel): bf16 weight layouts + fused bias ----------------
__global__ __launch_bounds__(256) void k_pre(const float* __restrict__ W1, const float* __restrict__ W2,
                      const float* __restrict__ W_ih, const float* __restrict__ W_hh,
                      const float* __restrict__ b_ih, const float* __restrict__ b_hh,
                      u16* W1T, u16* W2T, u16* WihB, u16* WhhB, float* bsum) {
    int gi = blockIdx.x * 256 + threadIdx.x;     // 64 blocks -> 16384 threads
    for (int i = gi; i < 128 * 32; i += 16384) { int c = i >> 5, k = i & 31; W1T[i] = f2b(W1[k * 128 + c]); }
    for (int i = gi; i < 128 * 128; i += 16384) { int c = i >> 7, k = i & 127; W2T[i] = f2b(W2[k * 128 + c]); }
    for (int i = gi; i < 256 * 128; i += 16384) WihB[i] = f2b(W_ih[i]);
    for (int i = gi; i < 256 * 64; i += 16384) WhhB[i] = f2b(W_hh[i]);
    if (gi < 256) bsum[gi] = b_ih[gi] + b_hh[gi];
}

// ---------------- adjacency -> bitmask, TRANSPOSED: bmT[b][wd(32)][row(1024)] u32 ----------------
__global__ __launch_bounds__(256) void k_mask(const int* __restrict__ adj, u32* __restrict__ bmT) {
    int gw = (blockIdx.x * 256 + threadIdx.x) >> 6;  // 4096 waves
    int lane = threadIdx.x & 63;
    int base = gw << 4;                              // 16 consecutive words per wave
#pragma unroll 4
    for (int it = 0; it < 16; ++it) {
        int u = base + it;
        unsigned long long m = __ballot(adj[((size_t)u << 6) + lane] > 0);
        if (lane == 0) {
            int g = u & 15;          // 64-j group -> words 2g, 2g+1
            int bi = u >> 4;
            int b = bi >> 10, i = bi & 1023;
            bmT[(((b << 5) + 2 * g) << 10) + i]     = (u32)m;
            bmT[(((b << 5) + 2 * g + 1) << 10) + i] = (u32)(m >> 32);
        }
    }
}

// WhT fragment-linear layout: 8KB per jc: [bt][jc(32)][tc(8)][lane][8e]

// ---------------- GAT layer-1 projection (MFMA): x -> Wh1 frag-linear + s vectors ----------------
__global__ __launch_bounds__(256) void k_projA(const float* __restrict__ x, const u16* __restrict__ W1T,
                                               const float* __restrict__ a1,
                                               u16* __restrict__ WhT, float* __restrict__ ssrc,
                                               float* __restrict__ sdst) {
    __shared__ float tile[64][132];
    __shared__ float sA[256];
    int bt = blockIdx.x >> 4, i0 = (blockIdx.x & 15) << 6;
    int b = bt >> 4, t = bt & 15;
    int tid = threadIdx.x, w = tid >> 6, l = tid & 63;
    int lr = l & 15, lg = l >> 4;
    sA[tid] = a1[tid];
    int i = i0 + 16 * w + lr;
    const float* xp = x + ((size_t)((b << 10) + i) * TT + t) * FIN + 8 * lg;
    float4 x0 = *(const float4*)xp;
    float4 x1 = *(const float4*)(xp + 4);
    short8 af;
    af[0] = (short)f2b(x0.x); af[1] = (short)f2b(x0.y); af[2] = (short)f2b(x0.z); af[3] = (short)f2b(x0.w);
    af[4] = (short)f2b(x1.x); af[5] = (short)f2b(x1.y); af[6] = (short)f2b(x1.z); af[7] = (short)f2b(x1.w);
    f32x4 zz = {0.f, 0.f, 0.f, 0.f};
#pragma unroll
    for (int tc = 0; tc < 8; ++tc) {
        short8 bf = *(const short8*)(W1T + ((16 * tc + lr) << 5) + 8 * lg);
        f32x4 d = __builtin_amdgcn_mfma_f32_16x16x32_bf16(af, bf, zz, 0, 0, 0);
#pragma unroll
        for (int r = 0; r < 4; ++r) tile[16 * w + 4 * lg + r][16 * tc + lr] = d[r];
    }
    __syncthreads();
    if (tid < 128) {
        int r = tid & 63;
        const float* av = sA + ((tid < 64) ? 0 : 128);
        float s = 0.f;
#pragma unroll 4
        for (int c = 0; c < 128; ++c) s += tile[r][c] * av[c];
        ((tid < 64) ? ssrc : sdst)[(bt << 10) + i0 + r] = s;
    }
    {   // write frag-linear: jc = (i0>>5)+hh2, 32 rows each
        int c = tid & 127, hh2 = tid >> 7;
        u16 tmp[32];
#pragma unroll
        for (int j = 0; j < 32; ++j) tmp[j] = f2b(tile[32 * hh2 + j][c]);
        int tc = c >> 4, lr2 = c & 15;
        u16* dst = WhT + (size_t)bt * 131072 + ((i0 >> 5) + hh2) * 4096 + tc * 512 + lr2 * 8;
#pragma unroll
        for (int lg2 = 0; lg2 < 4; ++lg2) *(short8*)(dst + lg2 * 128) = *(const short8*)(tmp + 8 * lg2);
    }
}

// ================ shared attn main-loop macros ================
#define ATTN_PROLOGUE                                                                \
    __shared__ __align__(16) u16 Bbuf[2][8192];                                      \
    __shared__ __align__(16) float Ej[1024];                                         \
    __shared__ __align__(16) float Fj[1024];                                         \
    int bt = blockIdx.x >> 2, i0b = (blockIdx.x & 3) << 8;                           \
    int b = bt >> 4;                                                                 \
    int tid = threadIdx.x, wv = tid >> 6, l = tid & 63;                              \
    int lr = l & 15, lg = l >> 4;                                                    \
    const u16* wbase = WhT + (size_t)bt * 131072;                                    \
    gload_lds16(wbase + (wv << 10) + l * 8,       &Bbuf[0][(wv << 10)]);             \
    gload_lds16(wbase + (wv << 10) + 512 + l * 8, &Bbuf[0][(wv << 10) + 512]);       \
    for (int k = tid; k < 1024; k += 512) {                                          \
        float sdv = sdst[(bt << 10) + k];                                            \
        Ej[k] = __expf(sdv);                                                         \
        Fj[k] = __expf(0.2f * sdv);                                                  \
    }                                                                                \
    int rb = i0b + (wv << 5);                                                        \
    const u32* mbase = bmT + ((size_t)b << 15);                                      \
    u32 mw0 = mbase[rb + lr];                                                        \
    u32 mw1 = mbase[rb + 16 + lr];                                                   \
    u32 mw2 = mbase[1024 + rb + lr];                                                 \
    u32 mw3 = mbase[1024 + rb + 16 + lr];                                            \
    float si0 = ssrc[(bt << 10) + rb + lr];                                          \
    float si1 = ssrc[(bt << 10) + rb + 16 + lr];                                     \
    float Ei0 = __expf(si0), Fi0 = __expf(0.2f * si0);                               \
    float Ei1 = __expf(si1), Fi1 = __expf(0.2f * si1);                               \
    f32x4 acc[2][8];                                                                 \
    _Pragma("unroll")                                                                \
    for (int rt = 0; rt < 2; ++rt)                                                   \
        _Pragma("unroll")                                                            \
        for (int tc = 0; tc < 8; ++tc) acc[rt][tc] = (f32x4){0.f, 0.f, 0.f, 0.f};    \
    f32x4 accd[2];                                                                   \
    accd[0] = (f32x4){0.f, 0.f, 0.f, 0.f};                                           \
    accd[1] = (f32x4){0.f, 0.f, 0.f, 0.f};                                           \
    short8 bone;                                                                     \
    _Pragma("unroll")                                                                \
    for (int e = 0; e < 8; ++e) bone[e] = (short)0x3F80;                             \
    __syncthreads();

#define PHALF(AF, EI, FI, WW)                                                        \
    {                                                                                \
        u32 byt = ((WW) >> (lg << 3)) & 0xFFu;                                       \
        float pA[8] = {fmaxf((EI) * e0.x, (FI) * f0.x), fmaxf((EI) * e0.y, (FI) * f0.y), \
                       fmaxf((EI) * e0.z, (FI) * f0.z), fmaxf((EI) * e0.w, (FI) * f0.w), \
                       fmaxf((EI) * e1.x, (FI) * f1.x), fmaxf((EI) * e1.y, (FI) * f1.y), \
                       fmaxf((EI) * e1.z, (FI) * f1.z), fmaxf((EI) * e1.w, (FI) * f1.w)}; \
        _Pragma("unroll")                                                            \
        for (int q = 0; q < 4; ++q) {                                                \
            u32 m0 = (u32)(-(int)((byt >> (2 * q)) & 1u));                           \
            u32 m1 = (u32)(-(int)((byt >> (2 * q + 1)) & 1u));                       \
            float p0 = __uint_as_float(__float_as_uint(pA[2 * q]) & m0);             \
            float p1 = __uint_as_float(__float_as_uint(pA[2 * q + 1]) & m1);         \
            asm("v_cvt_pk_bf16_f32 %0, %1, %2" : "=v"(AF.u[q]) : "v"(p0), "v"(p1));  \
        }                                                                            \
    }

#define COMPUTE(JC, CUR, JCL, W0, W1)                                                \
    {                                                                                \
        const float* ejp = Ej + ((JC) << 5) + (lg << 3);                             \
        const float* fjp = Fj + ((JC) << 5) + (lg << 3);                             \
        float4 e0 = *(const float4*)ejp, e1 = *(const float4*)(ejp + 4);             \
        float4 f0 = *(const float4*)fjp, f1 = *(const float4*)(fjp + 4);             \
        AFu af0, af1;                                                                \
        PHALF(af0, Ei0, Fi0, W0)                                                     \
        PHALF(af1, Ei1, Fi1, W1)                                                     \
        _Pragma("unroll")                                                            \
        for (int tc = 0; tc < 8; ++tc) {                                             \
            short8 bfr = *(const short8*)(&Bbuf[CUR][(JCL) * 4096 + tc * 512 + l * 8]); \
            acc[0][tc] = __builtin_amdgcn_mfma_f32_16x16x32_bf16(af0.s, bfr, acc[0][tc], 0, 0, 0); \
            acc[1][tc] = __builtin_amdgcn_mfma_f32_16x16x32_bf16(af1.s, bfr, acc[1][tc], 0, 0, 0); \
        }                                                                            \
        accd[0] = __builtin_amdgcn_mfma_f32_16x16x32_bf16(af0.s, bone, accd[0], 0, 0, 0); \
        accd[1] = __builtin_amdgcn_mfma_f32_16x16x32_bf16(af1.s, bone, accd[1], 0, 0, 0); \
    }

#define ATTN_MAIN_LOOP                                                               \
    for (int c = 0; c < 16; ++c) {                                                   \
        int cur = c & 1;                                                             \
        if (c < 15) {                                                                \
            gload_lds16(wbase + (c + 1) * 8192 + (wv << 10) + l * 8,       &Bbuf[cur ^ 1][(wv << 10)]);       \
            gload_lds16(wbase + (c + 1) * 8192 + (wv << 10) + 512 + l * 8, &Bbuf[cur ^ 1][(wv << 10) + 512]); \
        }                                                                            \
        u32 nw0 = 0, nw1 = 0, nw2 = 0, nw3 = 0;                                      \
        if (c < 15) {                                                                \
            const u32* mp = mbase + ((2 * c + 2) << 10);                             \
            nw0 = mp[rb + lr];        nw1 = mp[rb + 16 + lr];                        \
            nw2 = mp[1024 + rb + lr]; nw3 = mp[1024 + rb + 16 + lr];                 \
        }                                                                            \
        COMPUTE(2 * c,     cur, 0, mw0, mw1)                                         \
        COMPUTE(2 * c + 1, cur, 1, mw2, mw3)                                         \
        mw0 = nw0; mw1 = nw1; mw2 = nw2; mw3 = nw3;                                  \
        __syncthreads();                                                             \
    }

// ---------------- attn layer 1 + FUSED projB: outputs Wh2 frag-linear + s2 vectors.
// Per-rt epilogue: h tile (ELU'd, bf16, swizzled 4KB/wave) -> Wh2 = h @ W2 (K=128, accg[4]
// halves) -> frag-linear write + rank-1 s2 reductions (16-lane shfl_xor). ----------------
__global__ __launch_bounds__(512, 2) void k_attnH(const u16* __restrict__ WhT, const float* __restrict__ ssrc,
                                                  const float* __restrict__ sdst, const u32* __restrict__ bmT,
                                                  const u16* __restrict__ W2T, const float* __restrict__ a2,
                                                  u16* __restrict__ Wh2, float* __restrict__ s2s,
                                                  float* __restrict__ s2d) {
    ATTN_PROLOGUE
    ATTN_MAIN_LOOP

    char* hb = (char*)(&Bbuf[0][0]) + (wv << 12);   // 4KB wave-private h tile

#define EPI_STORE(RT)                                                                 \
    {                                                                                 \
        float inv[4];                                                                 \
        _Pragma("unroll")                                                             \
        for (int r = 0; r < 4; ++r) inv[r] = 1.f / accd[RT][r];                       \
        _Pragma("unroll")                                                             \
        for (int tc = 0; tc < 8; ++tc)                                                \
            _Pragma("unroll")                                                         \
            for (int r = 0; r < 4; ++r) {                                             \
                float v = acc[RT][tc][r] * inv[r];                                    \
                v = v > 0.f ? v : (__expf(v) - 1.f);                                  \
                v = v > 0.f ? v : (__expf(v) - 1.f);                                  \
                int row = (lg << 2) + r;                                              \
                int col = (tc << 4) + lr;                                             \
                *(u16*)(hb + (row << 8) + ((col << 1) ^ ((row & 7) << 4))) = f2b(v);  \
            }                                                                         \
        asm volatile("s_waitcnt lgkmcnt(0)" ::: "memory");                            \
        __builtin_amdgcn_sched_barrier(0);                                            \
    }

#define EPI_PROJB(RT)                                                                 \
    {                                                                                 \
        float ps[4], pd[4];                                                           \
        _Pragma("unroll")                                                             \
        for (int r = 0; r < 4; ++r) { ps[r] = 0.f; pd[r] = 0.f; }                     \
        int grow = i0b + (wv << 5) + ((RT) << 4);                                     \
        int jc = grow >> 5;                                                           \
        u16* wout = Wh2 + (size_t)bt * 131072 + jc * 4096;                            \
        int lg2 = 2 * (RT) + (lg >> 1);                                               \
        _Pragma("unroll")                                                             \
        for (int half = 0; half < 2; ++half) {                                        \
            f32x4 accg[4];                                                            \
            _Pragma("unroll")                                                         \
            for (int tq = 0; tq < 4; ++tq) accg[tq] = (f32x4){0.f, 0.f, 0.f, 0.f};    \
            _Pragma("unroll")                                                         \
            for (int ch = 0; ch < 4; ++ch) {                                          \
                short8 af2 = *(const short8*)(hb + (lr << 8) + (((ch << 6) + (lg << 4)) ^ ((lr & 7) << 4))); \
                _Pragma("unroll")                                                     \
                for (int tq = 0; tq < 4; ++tq) {                                      \
                    int tc2 = (half << 2) + tq;                                       \
                    short8 bf = *(const short8*)(W2T + ((16 * tc2 + lr) << 7) + (ch << 5) + 8 * lg); \
                    accg[tq] = __builtin_amdgcn_mfma_f32_16x16x32_bf16(af2, bf, accg[tq], 0, 0, 0); \
                }                                                                     \
            }                                                                         \
            _Pragma("unroll")                                                         \
            for (int tq = 0; tq < 4; ++tq) {                                          \
                int tc2 = (half << 2) + tq;                                           \
                float a2sv = a2[16 * tc2 + lr];                                       \
                float a2dv = a2[128 + 16 * tc2 + lr];                                 \
                short4v w4;                                                           \
                _Pragma("unroll")                                                     \
                for (int r = 0; r < 4; ++r) {                                         \
                    float wval = accg[tq][r];                                         \
                    ps[r] = __builtin_fmaf(wval, a2sv, ps[r]);                        \
                    pd[r] = __builtin_fmaf(wval, a2dv, pd[r]);                        \
                    w4[r] = (short)f2b(wval);                                         \
                }                                                                     \
                *(short4v*)(wout + tc2 * 512 + lg2 * 128 + lr * 8 + (lg & 1) * 4) = w4; \
            }                                                                         \
        }                                                                             \
        _Pragma("unroll")                                                             \
        for (int r = 0; r < 4; ++r) {                                                 \
            _Pragma("unroll")                                                         \
            for (int o = 1; o < 16; o <<= 1) {                                        \
                ps[r] += __shfl_xor(ps[r], o);                                        \
                pd[r] += __shfl_xor(pd[r], o);                                        \
            }                                                                         \
        }                                                                             \
        if (lr == 0) {                                                                \
            _Pragma("unroll")                                                         \
            for (int r = 0; r < 4; ++r) {                                             \
                int row = grow + 4 * lg + r;                                          \
                s2s[(bt << 10) + row] = ps[r];                                        \
                s2d[(bt << 10) + row] = pd[r];                                        \
            }                                                                         \
        }                                                                             \
    }

    EPI_STORE(0)
    EPI_PROJB(0)
    asm volatile("s_waitcnt lgkmcnt(0)" ::: "memory");   // rt0 tile reads done before overwrite
    __builtin_amdgcn_sched_barrier(0);
    EPI_STORE(1)
    EPI_PROJB(1)

#undef EPI_STORE
#undef EPI_PROJB
}

// ---------------- attn layer 2: fused Gx = elu2(h) @ W_ih^T + bias ----------------
__global__ __launch_bounds__(512, 2) void k_attnG(const u16* __restrict__ WhT, const float* __restrict__ ssrc,
                                                  const float* __restrict__ sdst, const u32* __restrict__ bmT,
                                                  const u16* __restrict__ WihB, const float* __restrict__ bsum,
                                                  u16* __restrict__ Gx) {
    ATTN_PROLOGUE
    ATTN_MAIN_LOOP

    int t = bt & 15;
    char* hb = (char*)(&Bbuf[0][0]) + (wv << 12);

#define EPI_STORE(RT)                                                                 \
    {                                                                                 \
        float inv[4];                                                                 \
        _Pragma("unroll")                                                             \
        for (int r = 0; r < 4; ++r) inv[r] = 1.f / accd[RT][r];                       \
        _Pragma("unroll")                                                             \
        for (int tc = 0; tc < 8; ++tc)                                                \
            _Pragma("unroll")                                                         \
            for (int r = 0; r < 4; ++r) {                                             \
                float v = acc[RT][tc][r] * inv[r];                                    \
                v = v > 0.f ? v : (__expf(v) - 1.f);                                  \
                v = v > 0.f ? v : (__expf(v) - 1.f);                                  \
                int row = (lg << 2) + r;                                              \
                int col = (tc << 4) + lr;                                             \
                *(u16*)(hb + (row << 8) + ((col << 1) ^ ((row & 7) << 4))) = f2b(v);  \
            }                                                                         \
        asm volatile("s_waitcnt lgkmcnt(0)" ::: "memory");                            \
        __builtin_amdgcn_sched_barrier(0);                                            \
    }

#define EPI_OUT_GX(RT)                                                                \
    {                                                                                 \
        int node = i0b + (wv << 5) + ((RT) << 4);                                     \
        int grpx = (b << 6) + (node >> 4);                                            \
        u16* gdst = Gx + (size_t)t * 1048576 + (size_t)grpx * 4096 + l * 8;           \
        _Pragma("unroll")                                                             \
        for (int half = 0; half < 2; ++half) {                                        \
            f32x4 accg[8];                                                            \
            _Pragma("unroll")                                                         \
            for (int tq = 0; tq < 8; ++tq) accg[tq] = (f32x4){0.f, 0.f, 0.f, 0.f};    \
            _Pragma("unroll")                                                         \
            for (int ch = 0; ch < 4; ++ch) {                                          \
                short8 af2 = *(const short8*)(hb + (lr << 8) + (((ch << 6) + (lg << 4)) ^ ((lr & 7) << 4))); \
                _Pragma("unroll")                                                     \
                for (int tq = 0; tq < 8; ++tq) {                                      \
                    int tc = (half << 3) + tq;                                        \
                    short8 bf = *(const short8*)(WihB + ((16 * tc + lr) << 7) + (ch << 5) + 8 * lg); \
                    accg[tq] = __builtin_amdgcn_mfma_f32_16x16x32_bf16(af2, bf, accg[tq], 0, 0, 0); \
                }                                                                     \
            }                                                                         \
            _Pragma("unroll")                                                         \
            for (int qq = 0; qq < 4; ++qq) {                                          \
                int tc0 = (half << 3) + 2 * qq;                                       \
                short8 v;                                                             \
                _Pragma("unroll")                                                     \
                for (int r = 0; r < 4; ++r) {                                         \
                    v[r]     = (short)f2b(accg[2 * qq][r]     + bsum[(tc0 << 4) + lr]); \
                    v[4 + r] = (short)f2b(accg[2 * qq + 1][r] + bsum[((tc0 + 1) << 4) + lr]); \
                }                                                                     \
                *(short8*)(gdst + ((half << 2) + qq) * 512) = v;                      \
            }                                                                         \
        }                                                                             \
    }

    EPI_STORE(0)
    EPI_OUT_GX(0)
    asm volatile("s_waitcnt lgkmcnt(0)" ::: "memory");   // rt0 tile reads done before overwrite
    __builtin_amdgcn_sched_barrier(0);
    EPI_STORE(1)
    EPI_OUT_GX(1)

#undef EPI_STORE
#undef EPI_OUT_GX
}

#undef ATTN_PROLOGUE
#undef ATTN_MAIN_LOOP
#undef PHALF
#undef COMPUTE

// ---------------- LSTM recurrence: 4 waves/block, wave w owns gate-tiles {w,w+4,w+8,w+12}
// (= i/f/g/o for hidden cols [16w,16w+16)); h exchanged via LDS; fused MLP on wave 0 ----------------
__global__ __launch_bounds__(256, 1) void k_lstm(const u16* __restrict__ Gx, const u16* __restrict__ WhhB,
                                                 const float* __restrict__ Wo1, const float* __restrict__ bo1,
                                                 const float* __restrict__ Wo2, const float* __restrict__ bo2,
                                                 float* __restrict__ out) {
    __shared__ u16 hls[16 * 72];
    __shared__ float hf[16 * 65];
    __shared__ float wo1[64 * 32];
    __shared__ float wo2[32];
    int grp = blockIdx.x;
    int m0 = grp << 4;
    int tid = threadIdx.x, wv = tid >> 6, l = tid & 63;
    int lr = l & 15, lg = l >> 4;
    for (int k = tid; k < 64 * 32; k += 256) wo1[k] = Wo1[k];
    if (tid < 32) wo2[tid] = Wo2[tid];
    for (int k = tid; k < 16 * 72; k += 256) hls[k] = 0;
    short8 bh[4][2];
#pragma unroll
    for (int tq = 0; tq < 4; ++tq)
#pragma unroll
        for (int ch = 0; ch < 2; ++ch)
            bh[tq][ch] = *(const short8*)(WhhB + ((16 * (wv + 4 * tq) + lr) << 6) + 32 * ch + 8 * lg);
    float cst[4], hreg[4];
#pragma unroll
    for (int r = 0; r < 4; ++r) { cst[r] = 0.f; hreg[r] = 0.f; }
    int sub = wv & 1;
    // Gx fragments for this wave: q = (wv>>1) + 2*tq
    const u16* gp = Gx + ((size_t)grp << 12) + ((size_t)(wv >> 1) << 9) + l * 8;
    short8 gx0[4], gx1[4];
#pragma unroll
    for (int tq = 0; tq < 4; ++tq) gx0[tq] = *(const short8*)(gp + tq * 1024);
    __syncthreads();
#pragma unroll
    for (int t = 0; t < TT; ++t) {
        if (t < 15) {     // prefetch next step's fragments
#pragma unroll
            for (int tq = 0; tq < 4; ++tq) {
                short8 v = *(const short8*)(gp + (size_t)(t + 1) * 1048576 + tq * 1024);
                if (t & 1) gx0[tq] = v; else gx1[tq] = v;
            }
        }
        f32x4 acc[4];
#pragma unroll
        for (int tq = 0; tq < 4; ++tq) {
            short8 v = (t & 1) ? gx1[tq] : gx0[tq];
#pragma unroll
            for (int r = 0; r < 4; ++r)
                acc[tq][r] = b2f((u16)v[(sub << 2) + r]);
        }
#pragma unroll
        for (int ch = 0; ch < 2; ++ch) {
            short8 af = *(const short8*)(hls + lr * 72 + 32 * ch + 8 * lg);
#pragma unroll
            for (int tq = 0; tq < 4; ++tq)
                acc[tq] = __builtin_amdgcn_mfma_f32_16x16x32_bf16(af, bh[tq][ch], acc[tq], 0, 0, 0);
        }
#pragma unroll
        for (int r = 0; r < 4; ++r) {
            float iv = fsig(acc[0][r]);
            float fv = fsig(acc[1][r]);
            float gv = ftanh(acc[2][r]);
            float ov = fsig(acc[3][r]);
            float cn = __builtin_fmaf(fv, cst[r], iv * gv);
            cst[r] = cn;
            hreg[r] = ov * ftanh(cn);
        }
        __syncthreads();     // all waves done reading hls
#pragma unroll
        for (int r = 0; r < 4; ++r)
            hls[(4 * lg + r) * 72 + 16 * wv + lr] = f2b(hreg[r]);
        __syncthreads();     // h ready for next step
    }
#pragma unroll
    for (int r = 0; r < 4; ++r)
        hf[(4 * lg + r) * 65 + 16 * wv + lr] = hreg[r];
    __syncthreads();
    if (wv == 0) {
        int r = lr, p = lg;
        float hid[8];
#pragma unroll
        for (int q = 0; q < 8; ++q) hid[q] = bo1[8 * p + q];
        for (int j = 0; j < 64; ++j) {
            float hv = hf[r * 65 + j];
#pragma unroll
            for (int q = 0; q < 8; ++q) hid[q] += hv * wo1[j * 32 + 8 * p + q];
        }
        float po = 0.f;
#pragma unroll
        for (int q = 0; q < 8; ++q) po += fmaxf(hid[q], 0.f) * wo2[8 * p + q];
        po += __shfl_xor(po, 16);
        po += __shfl_xor(po, 32);
        if (p == 0) out[m0 + r] = po + bo2[0];
    }
}

extern "C" void kernel_launch(void* const* d_in, const int* in_sizes, int n_in,
                              void* d_out, int out_size, void* d_ws, size_t ws_size,
                              hipStream_t stream) {
    const float* x    = (const float*)d_in[0];
    const int*   adj  = (const int*)d_in[1];
    const float* W1   = (const float*)d_in[2];
    const float* a1   = (const float*)d_in[3];
    const float* W2   = (const float*)d_in[4];
    const float* a2   = (const float*)d_in[5];
    const float* W_ih = (const float*)d_in[6];
    const float* W_hh = (const float*)d_in[7];
    const float* b_ih = (const float*)d_in[8];
    const float* b_hh = (const float*)d_in[9];
    const float* Wo1  = (const float*)d_in[10];
    const float* bo1  = (const float*)d_in[11];
    const float* Wo2  = (const float*)d_in[12];
    const float* bo2  = (const float*)d_in[13];
    float* out = (float*)d_out;

    char* w = (char*)d_ws;
    const size_t SLOT = (size_t)8388608 * sizeof(u16);   // 16.78 MB
    u16* A  = (u16*)w;
    u16* Bf = (u16*)(w + SLOT);
    u16* C  = (u16*)(w + 2 * SLOT);
    char* sm = w + 3 * SLOT;
    float* s1s = (float*)sm;
    float* s1d = s1s + 65536;
    float* s2s = s1d + 65536;
    float* s2d = s2s + 65536;
    u32* BM  = (u32*)(s2d + 65536);      // 131072 words (512 KB), transposed layout
    u16* W1T = (u16*)(BM + 131072);      // 4096
    u16* W2T = W1T + 4096;               // 16384
    u16* WihB = W2T + 16384;             // 32768
    u16* WhhB = WihB + 32768;            // 16384
    float* BS = (float*)(WhhB + 16384);  // 256
    u16* Gx = Bf;                        // Bf free until Gx (attnH no longer writes h)

    k_pre<<<64, 256, 0, stream>>>(W1, W2, W_ih, W_hh, b_ih, b_hh, W1T, W2T, WihB, WhhB, BS);
    k_mask<<<1024, 256, 0, stream>>>(adj, BM);
    k_projA<<<1024, 256, 0, stream>>>(x, W1T, a1, A, s1s, s1d);
    k_attnH<<<256, 512, 0, stream>>>(A, s1s, s1d, BM, W2T, a2, C, s2s, s2d);
    k_attnG<<<256, 512, 0, stream>>>(C, s2s, s2d, BM, WihB, BS, Gx);
    k_lstm<<<256, 256, 0, stream>>>(Gx, WhhB, Wo1, bo1, Wo2, bo2, out);
}

// Round 19
// 151.395 us; speedup vs baseline: 2.5435x; 1.0379x over previous
//
#include <hip/hip_runtime.h>
#include <hip/hip_bf16.h>
#include <math.h>

#define BB 4
#define NN 1024
#define TT 16
#define FIN 32
#define HH 128
#define LH 64
#define MLPH 32

typedef __attribute__((ext_vector_type(8))) short short8;
typedef __attribute__((ext_vector_type(4))) short short4v;
typedef __attribute__((ext_vector_type(4))) float f32x4;
typedef unsigned short u16;
typedef unsigned int u32;

union AFu { u32 u[4]; short8 s; };

__device__ __forceinline__ u16 f2b(float f) {
    union { float f; u32 u; } v; v.f = f;
    u32 u = v.u;
    return (u16)((u + 0x7FFFu + ((u >> 16) & 1u)) >> 16);
}
__device__ __forceinline__ float b2f(u16 h) {
    union { u32 u; float f; } v; v.u = ((u32)h) << 16;
    return v.f;
}
__device__ __forceinline__ float frcp(float x) {
    float r; asm("v_rcp_f32 %0, %1" : "=v"(r) : "v"(x)); return r;
}
__device__ __forceinline__ float fsig(float x) {          // 1/(1+e^-x)
    return frcp(1.f + __expf(-x));
}
__device__ __forceinline__ float ftanh(float x) {         // 2*sig(2x)-1
    return __builtin_fmaf(2.f, frcp(1.f + __expf(-2.f * x)), -1.f);
}
__device__ __forceinline__ void gload_lds16(const void* g, void* l) {
    __builtin_amdgcn_global_load_lds((const __attribute__((address_space(1))) unsigned int*)g,
                                     (__attribute__((address_space(3))) unsigned int*)l, 16, 0, 0);
}

// ---------------- precompute (parallel): bf16 weight layouts + fused bias ----------------
__global__ __launch_bounds__(256) void k_pre(const float* __restrict__ W1, const float* __restrict__ W2,
                      const float* __restrict__ W_ih, const float* __restrict__ W_hh,
                      const float* __restrict__ b_ih, const float* __restrict__ b_hh,
                      u16* W1T, u16* W2T, u16* WihB, u16* WhhB, float* bsum) {
    int gi = blockIdx.x * 256 + threadIdx.x;     // 64 blocks -> 16384 threads
    for (int i = gi; i < 128 * 32; i += 16384) { int c = i >> 5, k = i & 31; W1T[i] = f2b(W1[k * 128 + c]); }
    for (int i = gi; i < 128 * 128; i += 16384) { int c = i >> 7, k = i & 127; W2T[i] = f2b(W2[k * 128 + c]); }
    for (int i = gi; i < 256 * 128; i += 16384) WihB[i] = f2b(W_ih[i]);
    for (int i = gi; i < 256 * 64; i += 16384) WhhB[i] = f2b(W_hh[i]);
    if (gi < 256) bsum[gi] = b_ih[gi] + b_hh[gi];
}

// ---------------- adjacency -> bitmask, TRANSPOSED: bmT[b][wd(32)][row(1024)] u32 ----------------
__global__ __launch_bounds__(256) void k_mask(const int* __restrict__ adj, u32* __restrict__ bmT) {
    int gw = (blockIdx.x * 256 + threadIdx.x) >> 6;  // 4096 waves
    int lane = threadIdx.x & 63;
    int base = gw << 4;                              // 16 consecutive words per wave
#pragma unroll 4
    for (int it = 0; it < 16; ++it) {
        int u = base + it;
        unsigned long long m = __ballot(adj[((size_t)u << 6) + lane] > 0);
        if (lane == 0) {
            int g = u & 15;          // 64-j group -> words 2g, 2g+1
            int bi = u >> 4;
            int b = bi >> 10, i = bi & 1023;
            bmT[(((b << 5) + 2 * g) << 10) + i]     = (u32)m;
            bmT[(((b << 5) + 2 * g + 1) << 10) + i] = (u32)(m >> 32);
        }
    }
}

// WhT fragment-linear layout: 8KB per jc: [bt][jc(32)][tc(8)][lane][8e]

// ---------------- GAT layer-1 projection (MFMA): x -> Wh1 frag-linear + s vectors ----------------
__global__ __launch_bounds__(256) void k_projA(const float* __restrict__ x, const u16* __restrict__ W1T,
                                               const float* __restrict__ a1,
                                               u16* __restrict__ WhT, float* __restrict__ ssrc,
                                               float* __restrict__ sdst) {
    __shared__ float tile[64][132];
    __shared__ float sA[256];
    int bt = blockIdx.x >> 4, i0 = (blockIdx.x & 15) << 6;
    int b = bt >> 4, t = bt & 15;
    int tid = threadIdx.x, w = tid >> 6, l = tid & 63;
    int lr = l & 15, lg = l >> 4;
    sA[tid] = a1[tid];
    int i = i0 + 16 * w + lr;
    const float* xp = x + ((size_t)((b << 10) + i) * TT + t) * FIN + 8 * lg;
    float4 x0 = *(const float4*)xp;
    float4 x1 = *(const float4*)(xp + 4);
    short8 af;
    af[0] = (short)f2b(x0.x); af[1] = (short)f2b(x0.y); af[2] = (short)f2b(x0.z); af[3] = (short)f2b(x0.w);
    af[4] = (short)f2b(x1.x); af[5] = (short)f2b(x1.y); af[6] = (short)f2b(x1.z); af[7] = (short)f2b(x1.w);
    f32x4 zz = {0.f, 0.f, 0.f, 0.f};
#pragma unroll
    for (int tc = 0; tc < 8; ++tc) {
        short8 bf = *(const short8*)(W1T + ((16 * tc + lr) << 5) + 8 * lg);
        f32x4 d = __builtin_amdgcn_mfma_f32_16x16x32_bf16(af, bf, zz, 0, 0, 0);
#pragma unroll
        for (int r = 0; r < 4; ++r) tile[16 * w + 4 * lg + r][16 * tc + lr] = d[r];
    }
    __syncthreads();
    if (tid < 128) {
        int r = tid & 63;
        const float* av = sA + ((tid < 64) ? 0 : 128);
        float s = 0.f;
#pragma unroll 4
        for (int c = 0; c < 128; ++c) s += tile[r][c] * av[c];
        ((tid < 64) ? ssrc : sdst)[(bt << 10) + i0 + r] = s;
    }
    {   // write frag-linear: jc = (i0>>5)+hh2, 32 rows each
        int c = tid & 127, hh2 = tid >> 7;
        u16 tmp[32];
#pragma unroll
        for (int j = 0; j < 32; ++j) tmp[j] = f2b(tile[32 * hh2 + j][c]);
        int tc = c >> 4, lr2 = c & 15;
        u16* dst = WhT + (size_t)bt * 131072 + ((i0 >> 5) + hh2) * 4096 + tc * 512 + lr2 * 8;
#pragma unroll
        for (int lg2 = 0; lg2 < 4; ++lg2) *(short8*)(dst + lg2 * 128) = *(const short8*)(tmp + 8 * lg2);
    }
}

// ================ shared attn main-loop macros (1024 thr, 16 waves, M=16 rows/wave) ================
#define ATTN_PROLOGUE                                                                \
    __shared__ __align__(16) u16 Bbuf[2][8192];                                      \
    __shared__ __align__(16) float Ej[1024];                                         \
    __shared__ __align__(16) float Fj[1024];                                         \
    __shared__ __align__(16) u16 Hls[16][2048];                                      \
    int bt = blockIdx.x >> 2, i0b = (blockIdx.x & 3) << 8;                           \
    int b = bt >> 4;                                                                 \
    int tid = threadIdx.x, wv = tid >> 6, l = tid & 63;                              \
    int lr = l & 15, lg = l >> 4;                                                    \
    const u16* wbase = WhT + (size_t)bt * 131072;                                    \
    gload_lds16(wbase + (wv << 9) + l * 8, &Bbuf[0][(wv << 9)]);                     \
    {                                                                                \
        float sdv = sdst[(bt << 10) + tid];                                          \
        Ej[tid] = __expf(sdv);                                                       \
        Fj[tid] = __expf(0.2f * sdv);                                                \
    }                                                                                \
    int rb = i0b + (wv << 4);                                                        \
    const u32* mbase = bmT + ((size_t)b << 15);                                      \
    u32 mw0 = mbase[rb + lr];                                                        \
    u32 mw1 = mbase[1024 + rb + lr];                                                 \
    float si0 = ssrc[(bt << 10) + rb + lr];                                          \
    float Ei0 = __expf(si0), Fi0 = __expf(0.2f * si0);                               \
    f32x4 acc[8];                                                                    \
    _Pragma("unroll")                                                                \
    for (int tc = 0; tc < 8; ++tc) acc[tc] = (f32x4){0.f, 0.f, 0.f, 0.f};            \
    f32x4 accd = (f32x4){0.f, 0.f, 0.f, 0.f};                                        \
    short8 bone;                                                                     \
    _Pragma("unroll")                                                                \
    for (int e = 0; e < 8; ++e) bone[e] = (short)0x3F80;                             \
    __syncthreads();

#define PHALF(AF, WW)                                                                \
    {                                                                                \
        u32 byt = ((WW) >> (lg << 3)) & 0xFFu;                                       \
        float pA[8] = {fmaxf(Ei0 * e0.x, Fi0 * f0.x), fmaxf(Ei0 * e0.y, Fi0 * f0.y), \
                       fmaxf(Ei0 * e0.z, Fi0 * f0.z), fmaxf(Ei0 * e0.w, Fi0 * f0.w), \
                       fmaxf(Ei0 * e1.x, Fi0 * f1.x), fmaxf(Ei0 * e1.y, Fi0 * f1.y), \
                       fmaxf(Ei0 * e1.z, Fi0 * f1.z), fmaxf(Ei0 * e1.w, Fi0 * f1.w)}; \
        _Pragma("unroll")                                                            \
        for (int q = 0; q < 4; ++q) {                                                \
            u32 m0 = (u32)(-(int)((byt >> (2 * q)) & 1u));                           \
            u32 m1 = (u32)(-(int)((byt >> (2 * q + 1)) & 1u));                       \
            float p0 = __uint_as_float(__float_as_uint(pA[2 * q]) & m0);             \
            float p1 = __uint_as_float(__float_as_uint(pA[2 * q + 1]) & m1);         \
            asm("v_cvt_pk_bf16_f32 %0, %1, %2" : "=v"(AF.u[q]) : "v"(p0), "v"(p1));  \
        }                                                                            \
    }

#define COMPUTE(JC, CUR, JCL, W0)                                                    \
    {                                                                                \
        const float* ejp = Ej + ((JC) << 5) + (lg << 3);                             \
        const float* fjp = Fj + ((JC) << 5) + (lg << 3);                             \
        float4 e0 = *(const float4*)ejp, e1 = *(const float4*)(ejp + 4);             \
        float4 f0 = *(const float4*)fjp, f1 = *(const float4*)(fjp + 4);             \
        AFu af0;                                                                     \
        PHALF(af0, W0)                                                               \
        _Pragma("unroll")                                                            \
        for (int tc = 0; tc < 8; ++tc) {                                             \
            short8 bfr = *(const short8*)(&Bbuf[CUR][(JCL) * 4096 + tc * 512 + l * 8]); \
            acc[tc] = __builtin_amdgcn_mfma_f32_16x16x32_bf16(af0.s, bfr, acc[tc], 0, 0, 0); \
        }                                                                            \
        accd = __builtin_amdgcn_mfma_f32_16x16x32_bf16(af0.s, bone, accd, 0, 0, 0);  \
    }

#define ATTN_MAIN_LOOP                                                               \
    for (int c = 0; c < 16; ++c) {                                                   \
        int cur = c & 1;                                                             \
        if (c < 15)                                                                  \
            gload_lds16(wbase + (c + 1) * 8192 + (wv << 9) + l * 8, &Bbuf[cur ^ 1][(wv << 9)]); \
        u32 nw0 = 0, nw1 = 0;                                                        \
        if (c < 15) {                                                                \
            const u32* mp = mbase + ((2 * c + 2) << 10);                             \
            nw0 = mp[rb + lr];                                                       \
            nw1 = mp[1024 + rb + lr];                                                \
        }                                                                            \
        COMPUTE(2 * c,     cur, 0, mw0)                                              \
        COMPUTE(2 * c + 1, cur, 1, mw1)                                              \
        mw0 = nw0; mw1 = nw1;                                                        \
        __syncthreads();                                                             \
    }

// h store: wave-private 4KB tile in Hls[wv], swizzled. row=(lg<<2)+r, col=tc*16+lr.
#define EPI_STORE_H                                                                  \
    {                                                                                \
        float inv[4];                                                                \
        _Pragma("unroll")                                                            \
        for (int r = 0; r < 4; ++r) inv[r] = 1.f / accd[r];                          \
        _Pragma("unroll")                                                            \
        for (int tc = 0; tc < 8; ++tc)                                               \
            _Pragma("unroll")                                                        \
            for (int r = 0; r < 4; ++r) {                                            \
                float v = acc[tc][r] * inv[r];                                       \
                v = v > 0.f ? v : (__expf(v) - 1.f);                                 \
                v = v > 0.f ? v : (__expf(v) - 1.f);                                 \
                int row = (lg << 2) + r;                                             \
                int col = (tc << 4) + lr;                                            \
                hb[(row << 7) + (col ^ ((row & 7) << 3))] = f2b(v);                  \
            }                                                                        \
    }

// ---------------- attn layer 1 + FUSED projB: outputs Wh2 frag-linear + s2 vectors ----------------
__global__ __launch_bounds__(1024, 1) void k_attnH(const u16* __restrict__ WhT, const float* __restrict__ ssrc,
                                                   const float* __restrict__ sdst, const u32* __restrict__ bmT,
                                                   const u16* __restrict__ W2T, const float* __restrict__ a2,
                                                   u16* __restrict__ Wh2, float* __restrict__ s2s,
                                                   float* __restrict__ s2d) {
    ATTN_PROLOGUE
    ATTN_MAIN_LOOP

    u16* hb = &Hls[wv][0];
    EPI_STORE_H

    // projB: Wh2[rows rb..rb+15] = h @ W2, frag-linear write + rank-1 s2 reductions
    {
        float ps[4], pd[4];
#pragma unroll
        for (int r = 0; r < 4; ++r) { ps[r] = 0.f; pd[r] = 0.f; }
        int jc2 = rb >> 5;
        int lgf = ((wv & 1) << 1) + (lg >> 1);
        u16* wout = Wh2 + (size_t)bt * 131072 + jc2 * 4096;
#pragma unroll
        for (int half = 0; half < 2; ++half) {
            f32x4 accg[4];
#pragma unroll
            for (int tq = 0; tq < 4; ++tq) accg[tq] = (f32x4){0.f, 0.f, 0.f, 0.f};
#pragma unroll
            for (int ch = 0; ch < 4; ++ch) {
                short8 af2 = *(const short8*)(hb + (lr << 7) + (((ch << 5) + (lg << 3)) ^ ((lr & 7) << 3)));
#pragma unroll
                for (int tq = 0; tq < 4; ++tq) {
                    int tc2 = (half << 2) + tq;
                    short8 bf = *(const short8*)(W2T + ((16 * tc2 + lr) << 7) + (ch << 5) + 8 * lg);
                    accg[tq] = __builtin_amdgcn_mfma_f32_16x16x32_bf16(af2, bf, accg[tq], 0, 0, 0);
                }
            }
#pragma unroll
            for (int tq = 0; tq < 4; ++tq) {
                int tc2 = (half << 2) + tq;
                float a2sv = a2[16 * tc2 + lr];
                float a2dv = a2[128 + 16 * tc2 + lr];
                short4v w4;
#pragma unroll
                for (int r = 0; r < 4; ++r) {
                    float wval = accg[tq][r];
                    ps[r] = __builtin_fmaf(wval, a2sv, ps[r]);
                    pd[r] = __builtin_fmaf(wval, a2dv, pd[r]);
                    w4[r] = (short)f2b(wval);
                }
                *(short4v*)(wout + tc2 * 512 + lgf * 128 + lr * 8 + (lg & 1) * 4) = w4;
            }
        }
#pragma unroll
        for (int r = 0; r < 4; ++r) {
#pragma unroll
            for (int o = 1; o < 16; o <<= 1) {
                ps[r] += __shfl_xor(ps[r], o);
                pd[r] += __shfl_xor(pd[r], o);
            }
        }
        if (lr == 0) {
#pragma unroll
            for (int r = 0; r < 4; ++r) {
                int row = rb + 4 * lg + r;
                s2s[(bt << 10) + row] = ps[r];
                s2d[(bt << 10) + row] = pd[r];
            }
        }
    }
}

// ---------------- attn layer 2: fused Gx = elu2(h) @ W_ih^T + bias ----------------
__global__ __launch_bounds__(1024, 1) void k_attnG(const u16* __restrict__ WhT, const float* __restrict__ ssrc,
                                                   const float* __restrict__ sdst, const u32* __restrict__ bmT,
                                                   const u16* __restrict__ WihB, const float* __restrict__ bsum,
                                                   u16* __restrict__ Gx) {
    ATTN_PROLOGUE
    ATTN_MAIN_LOOP

    u16* hb = &Hls[wv][0];
    EPI_STORE_H

    int t = bt & 15;
    int grpx = (b << 6) + (rb >> 4);
    u16* gdst = Gx + (size_t)t * 1048576 + (size_t)grpx * 4096 + l * 8;
#pragma unroll
    for (int half = 0; half < 2; ++half) {
        f32x4 accg[8];
#pragma unroll
        for (int tq = 0; tq < 8; ++tq) accg[tq] = (f32x4){0.f, 0.f, 0.f, 0.f};
#pragma unroll
        for (int ch = 0; ch < 4; ++ch) {
            short8 af2 = *(const short8*)(hb + (lr << 7) + (((ch << 5) + (lg << 3)) ^ ((lr & 7) << 3)));
#pragma unroll
            for (int tq = 0; tq < 8; ++tq) {
                int tc = (half << 3) + tq;
                short8 bf = *(const short8*)(WihB + ((16 * tc + lr) << 7) + (ch << 5) + 8 * lg);
                accg[tq] = __builtin_amdgcn_mfma_f32_16x16x32_bf16(af2, bf, accg[tq], 0, 0, 0);
            }
        }
#pragma unroll
        for (int qq = 0; qq < 4; ++qq) {
            int tc0 = (half << 3) + 2 * qq;
            short8 v;
#pragma unroll
            for (int r = 0; r < 4; ++r) {
                v[r]     = (short)f2b(accg[2 * qq][r]     + bsum[(tc0 << 4) + lr]);
                v[4 + r] = (short)f2b(accg[2 * qq + 1][r] + bsum[((tc0 + 1) << 4) + lr]);
            }
            *(short8*)(gdst + ((half << 2) + qq) * 512) = v;
        }
    }
}

#undef ATTN_PROLOGUE
#undef ATTN_MAIN_LOOP
#undef PHALF
#undef COMPUTE
#undef EPI_STORE_H

// ---------------- LSTM recurrence: 4 waves/block, wave w owns gate-tiles {w,w+4,w+8,w+12}
// (= i/f/g/o for hidden cols [16w,16w+16)); h exchanged via LDS; fused MLP on wave 0 ----------------
__global__ __launch_bounds__(256, 1) void k_lstm(const u16* __restrict__ Gx, const u16* __restrict__ WhhB,
                                                 const float* __restrict__ Wo1, const float* __restrict__ bo1,
                                                 const float* __restrict__ Wo2, const float* __restrict__ bo2,
                                                 float* __restrict__ out) {
    __shared__ u16 hls[16 * 72];
    __shared__ float hf[16 * 65];
    __shared__ float wo1[64 * 32];
    __shared__ float wo2[32];
    int grp = blockIdx.x;
    int m0 = grp << 4;
    int tid = threadIdx.x, wv = tid >> 6, l = tid & 63;
    int lr = l & 15, lg = l >> 4;
    for (int k = tid; k < 64 * 32; k += 256) wo1[k] = Wo1[k];
    if (tid < 32) wo2[tid] = Wo2[tid];
    for (int k = tid; k < 16 * 72; k += 256) hls[k] = 0;
    short8 bh[4][2];
#pragma unroll
    for (int tq = 0; tq < 4; ++tq)
#pragma unroll
        for (int ch = 0; ch < 2; ++ch)
            bh[tq][ch] = *(const short8*)(WhhB + ((16 * (wv + 4 * tq) + lr) << 6) + 32 * ch + 8 * lg);
    float cst[4], hreg[4];
#pragma unroll
    for (int r = 0; r < 4; ++r) { cst[r] = 0.f; hreg[r] = 0.f; }
    int sub = wv & 1;
    // Gx fragments for this wave: q = (wv>>1) + 2*tq
    const u16* gp = Gx + ((size_t)grp << 12) + ((size_t)(wv >> 1) << 9) + l * 8;
    short8 gx0[4], gx1[4];
#pragma unroll
    for (int tq = 0; tq < 4; ++tq) gx0[tq] = *(const short8*)(gp + tq * 1024);
    __syncthreads();
#pragma unroll
    for (int t = 0; t < TT; ++t) {
        if (t < 15) {     // prefetch next step's fragments
#pragma unroll
            for (int tq = 0; tq < 4; ++tq) {
                short8 v = *(const short8*)(gp + (size_t)(t + 1) * 1048576 + tq * 1024);
                if (t & 1) gx0[tq] = v; else gx1[tq] = v;
            }
        }
        f32x4 acc[4];
#pragma unroll
        for (int tq = 0; tq < 4; ++tq) {
            short8 v = (t & 1) ? gx1[tq] : gx0[tq];
#pragma unroll
            for (int r = 0; r < 4; ++r)
                acc[tq][r] = b2f((u16)v[(sub << 2) + r]);
        }
#pragma unroll
        for (int ch = 0; ch < 2; ++ch) {
            short8 af = *(const short8*)(hls + lr * 72 + 32 * ch + 8 * lg);
#pragma unroll
            for (int tq = 0; tq < 4; ++tq)
                acc[tq] = __builtin_amdgcn_mfma_f32_16x16x32_bf16(af, bh[tq][ch], acc[tq], 0, 0, 0);
        }
#pragma unroll
        for (int r = 0; r < 4; ++r) {
            float iv = fsig(acc[0][r]);
            float fv = fsig(acc[1][r]);
            float gv = ftanh(acc[2][r]);
            float ov = fsig(acc[3][r]);
            float cn = __builtin_fmaf(fv, cst[r], iv * gv);
            cst[r] = cn;
            hreg[r] = ov * ftanh(cn);
        }
        __syncthreads();     // all waves done reading hls
#pragma unroll
        for (int r = 0; r < 4; ++r)
            hls[(4 * lg + r) * 72 + 16 * wv + lr] = f2b(hreg[r]);
        __syncthreads();     // h ready for next step
    }
#pragma unroll
    for (int r = 0; r < 4; ++r)
        hf[(4 * lg + r) * 65 + 16 * wv + lr] = hreg[r];
    __syncthreads();
    if (wv == 0) {
        int r = lr, p = lg;
        float hid[8];
#pragma unroll
        for (int q = 0; q < 8; ++q) hid[q] = bo1[8 * p + q];
        for (int j = 0; j < 64; ++j) {
            float hv = hf[r * 65 + j];
#pragma unroll
            for (int q = 0; q < 8; ++q) hid[q] += hv * wo1[j * 32 + 8 * p + q];
        }
        float po = 0.f;
#pragma unroll
        for (int q = 0; q < 8; ++q) po += fmaxf(hid[q], 0.f) * wo2[8 * p + q];
        po += __shfl_xor(po, 16);
        po += __shfl_xor(po, 32);
        if (p == 0) out[m0 + r] = po + bo2[0];
    }
}

extern "C" void kernel_launch(void* const* d_in, const int* in_sizes, int n_in,
                              void* d_out, int out_size, void* d_ws, size_t ws_size,
                              hipStream_t stream) {
    const float* x    = (const float*)d_in[0];
    const int*   adj  = (const int*)d_in[1];
    const float* W1   = (const float*)d_in[2];
    const float* a1   = (const float*)d_in[3];
    const float* W2   = (const float*)d_in[4];
    const float* a2   = (const float*)d_in[5];
    const float* W_ih = (const float*)d_in[6];
    const float* W_hh = (const float*)d_in[7];
    const float* b_ih = (const float*)d_in[8];
    const float* b_hh = (const float*)d_in[9];
    const float* Wo1  = (const float*)d_in[10];
    const float* bo1  = (const float*)d_in[11];
    const float* Wo2  = (const float*)d_in[12];
    const float* bo2  = (const float*)d_in[13];
    float* out = (float*)d_out;

    char* w = (char*)d_ws;
    const size_t SLOT = (size_t)8388608 * sizeof(u16);   // 16.78 MB
    u16* A  = (u16*)w;
    u16* Bf = (u16*)(w + SLOT);
    u16* C  = (u16*)(w + 2 * SLOT);
    char* sm = w + 3 * SLOT;
    float* s1s = (float*)sm;
    float* s1d = s1s + 65536;
    float* s2s = s1d + 65536;
    float* s2d = s2s + 65536;
    u32* BM  = (u32*)(s2d + 65536);      // 131072 words (512 KB), transposed layout
    u16* W1T = (u16*)(BM + 131072);      // 4096
    u16* W2T = W1T + 4096;               // 16384
    u16* WihB = W2T + 16384;             // 32768
    u16* WhhB = WihB + 32768;            // 16384
    float* BS = (float*)(WhhB + 16384);  // 256
    u16* Gx = Bf;                        // Bf free (attnH no longer writes h)

    k_pre<<<64, 256, 0, stream>>>(W1, W2, W_ih, W_hh, b_ih, b_hh, W1T, W2T, WihB, WhhB, BS);
    k_mask<<<1024, 256, 0, stream>>>(adj, BM);
    k_projA<<<1024, 256, 0, stream>>>(x, W1T, a1, A, s1s, s1d);
    k_attnH<<<256, 1024, 0, stream>>>(A, s1s, s1d, BM, W2T, a2, C, s2s, s2d);
    k_attnG<<<256, 1024, 0, stream>>>(C, s2s, s2d, BM, WihB, BS, Gx);
    k_lstm<<<256, 256, 0, stream>>>(Gx, WhhB, Wo1, bo1, Wo2, bo2, out);
}

// Round 20
// 150.664 us; speedup vs baseline: 2.5559x; 1.0049x over previous
//
#include <hip/hip_runtime.h>
#include <hip/hip_bf16.h>
#include <math.h>

#define BB 4
#define NN 1024
#define TT 16
#define FIN 32
#define HH 128
#define LH 64
#define MLPH 32

typedef __attribute__((ext_vector_type(8))) short short8;
typedef __attribute__((ext_vector_type(4))) short short4v;
typedef __attribute__((ext_vector_type(4))) float f32x4;
typedef unsigned short u16;
typedef unsigned int u32;

union AFu { u32 u[4]; short8 s; };

__device__ __forceinline__ u16 f2b(float f) {
    union { float f; u32 u; } v; v.f = f;
    u32 u = v.u;
    return (u16)((u + 0x7FFFu + ((u >> 16) & 1u)) >> 16);
}
__device__ __forceinline__ float b2f(u16 h) {
    union { u32 u; float f; } v; v.u = ((u32)h) << 16;
    return v.f;
}
__device__ __forceinline__ float frcp(float x) {
    float r; asm("v_rcp_f32 %0, %1" : "=v"(r) : "v"(x)); return r;
}
__device__ __forceinline__ float fsig(float x) {          // 1/(1+e^-x)
    return frcp(1.f + __expf(-x));
}
__device__ __forceinline__ float ftanh(float x) {         // 2*sig(2x)-1
    return __builtin_fmaf(2.f, frcp(1.f + __expf(-2.f * x)), -1.f);
}
__device__ __forceinline__ void gload_lds16(const void* g, void* l) {
    __builtin_amdgcn_global_load_lds((const __attribute__((address_space(1))) unsigned int*)g,
                                     (__attribute__((address_space(3))) unsigned int*)l, 16, 0, 0);
}

// ---------------- precompute (parallel): bf16 weight layouts + fused bias ----------------
__global__ __launch_bounds__(256) void k_pre(const float* __restrict__ W1, const float* __restrict__ W2,
                      const float* __restrict__ W_ih, const float* __restrict__ W_hh,
                      const float* __restrict__ b_ih, const float* __restrict__ b_hh,
                      u16* W1T, u16* W2T, u16* WihB, u16* WhhB, float* bsum) {
    int gi = blockIdx.x * 256 + threadIdx.x;     // 64 blocks -> 16384 threads
    for (int i = gi; i < 128 * 32; i += 16384) { int c = i >> 5, k = i & 31; W1T[i] = f2b(W1[k * 128 + c]); }
    for (int i = gi; i < 128 * 128; i += 16384) { int c = i >> 7, k = i & 127; W2T[i] = f2b(W2[k * 128 + c]); }
    for (int i = gi; i < 256 * 128; i += 16384) WihB[i] = f2b(W_ih[i]);
    for (int i = gi; i < 256 * 64; i += 16384) WhhB[i] = f2b(W_hh[i]);
    if (gi < 256) bsum[gi] = b_ih[gi] + b_hh[gi];
}

// ---------------- adjacency -> bitmask, TRANSPOSED: bmT[b][wd(32)][row(1024)] u32 ----------------
__global__ __launch_bounds__(256) void k_mask(const int* __restrict__ adj, u32* __restrict__ bmT) {
    int gw = (blockIdx.x * 256 + threadIdx.x) >> 6;  // 4096 waves
    int lane = threadIdx.x & 63;
    int base = gw << 4;                              // 16 consecutive words per wave
#pragma unroll 4
    for (int it = 0; it < 16; ++it) {
        int u = base + it;
        unsigned long long m = __ballot(adj[((size_t)u << 6) + lane] > 0);
        if (lane == 0) {
            int g = u & 15;          // 64-j group -> words 2g, 2g+1
            int bi = u >> 4;
            int b = bi >> 10, i = bi & 1023;
            bmT[(((b << 5) + 2 * g) << 10) + i]     = (u32)m;
            bmT[(((b << 5) + 2 * g + 1) << 10) + i] = (u32)(m >> 32);
        }
    }
}

// WhT fragment-linear layout: 8KB per jc: [bt][jc(32)][tc(8)][lane][8e]

// ---------------- GAT layer-1 projection (MFMA): x -> Wh1 frag-linear + s vectors ----------------
__global__ __launch_bounds__(256) void k_projA(const float* __restrict__ x, const u16* __restrict__ W1T,
                                               const float* __restrict__ a1,
                                               u16* __restrict__ WhT, float* __restrict__ ssrc,
                                               float* __restrict__ sdst) {
    __shared__ float tile[64][132];
    __shared__ float sA[256];
    int bt = blockIdx.x >> 4, i0 = (blockIdx.x & 15) << 6;
    int b = bt >> 4, t = bt & 15;
    int tid = threadIdx.x, w = tid >> 6, l = tid & 63;
    int lr = l & 15, lg = l >> 4;
    sA[tid] = a1[tid];
    int i = i0 + 16 * w + lr;
    const float* xp = x + ((size_t)((b << 10) + i) * TT + t) * FIN + 8 * lg;
    float4 x0 = *(const float4*)xp;
    float4 x1 = *(const float4*)(xp + 4);
    short8 af;
    af[0] = (short)f2b(x0.x); af[1] = (short)f2b(x0.y); af[2] = (short)f2b(x0.z); af[3] = (short)f2b(x0.w);
    af[4] = (short)f2b(x1.x); af[5] = (short)f2b(x1.y); af[6] = (short)f2b(x1.z); af[7] = (short)f2b(x1.w);
    f32x4 zz = {0.f, 0.f, 0.f, 0.f};
#pragma unroll
    for (int tc = 0; tc < 8; ++tc) {
        short8 bf = *(const short8*)(W1T + ((16 * tc + lr) << 5) + 8 * lg);
        f32x4 d = __builtin_amdgcn_mfma_f32_16x16x32_bf16(af, bf, zz, 0, 0, 0);
#pragma unroll
        for (int r = 0; r < 4; ++r) tile[16 * w + 4 * lg + r][16 * tc + lr] = d[r];
    }
    __syncthreads();
    if (tid < 128) {
        int r = tid & 63;
        const float* av = sA + ((tid < 64) ? 0 : 128);
        float s = 0.f;
#pragma unroll 4
        for (int c = 0; c < 128; ++c) s += tile[r][c] * av[c];
        ((tid < 64) ? ssrc : sdst)[(bt << 10) + i0 + r] = s;
    }
    {   // write frag-linear: jc = (i0>>5)+hh2, 32 rows each
        int c = tid & 127, hh2 = tid >> 7;
        u16 tmp[32];
#pragma unroll
        for (int j = 0; j < 32; ++j) tmp[j] = f2b(tile[32 * hh2 + j][c]);
        int tc = c >> 4, lr2 = c & 15;
        u16* dst = WhT + (size_t)bt * 131072 + ((i0 >> 5) + hh2) * 4096 + tc * 512 + lr2 * 8;
#pragma unroll
        for (int lg2 = 0; lg2 < 4; ++lg2) *(short8*)(dst + lg2 * 128) = *(const short8*)(tmp + 8 * lg2);
    }
}

// ================ shared attn main-loop macros (1024 thr, 16 waves, M=16 rows/wave,
// 32KB chunks (4 jc) -> 8 barrier iterations instead of 16) ================
#define ATTN_PROLOGUE                                                                \
    __shared__ __align__(16) u16 Bbuf[2][16384];                                     \
    __shared__ __align__(16) float Ej[1024];                                         \
    __shared__ __align__(16) float Fj[1024];                                         \
    __shared__ __align__(16) u16 Hls[16][2048];                                      \
    int bt = blockIdx.x >> 2, i0b = (blockIdx.x & 3) << 8;                           \
    int b = bt >> 4;                                                                 \
    int tid = threadIdx.x, wv = tid >> 6, l = tid & 63;                              \
    int lr = l & 15, lg = l >> 4;                                                    \
    const u16* wbase = WhT + (size_t)bt * 131072;                                    \
    gload_lds16(wbase + (wv << 10) + l * 8,       &Bbuf[0][(wv << 10)]);             \
    gload_lds16(wbase + (wv << 10) + 512 + l * 8, &Bbuf[0][(wv << 10) + 512]);       \
    {                                                                                \
        float sdv = sdst[(bt << 10) + tid];                                          \
        Ej[tid] = __expf(sdv);                                                       \
        Fj[tid] = __expf(0.2f * sdv);                                                \
    }                                                                                \
    int rb = i0b + (wv << 4);                                                        \
    const u32* mbase = bmT + ((size_t)b << 15);                                      \
    u32 mw0 = mbase[rb + lr];                                                        \
    u32 mw1 = mbase[1024 + rb + lr];                                                 \
    u32 mw2 = mbase[2048 + rb + lr];                                                 \
    u32 mw3 = mbase[3072 + rb + lr];                                                 \
    float si0 = ssrc[(bt << 10) + rb + lr];                                          \
    float Ei0 = __expf(si0), Fi0 = __expf(0.2f * si0);                               \
    f32x4 acc[8];                                                                    \
    _Pragma("unroll")                                                                \
    for (int tc = 0; tc < 8; ++tc) acc[tc] = (f32x4){0.f, 0.f, 0.f, 0.f};            \
    f32x4 accd = (f32x4){0.f, 0.f, 0.f, 0.f};                                        \
    short8 bone;                                                                     \
    _Pragma("unroll")                                                                \
    for (int e = 0; e < 8; ++e) bone[e] = (short)0x3F80;                             \
    __syncthreads();

#define PHALF(AF, WW)                                                                \
    {                                                                                \
        u32 byt = ((WW) >> (lg << 3)) & 0xFFu;                                       \
        float pA[8] = {fmaxf(Ei0 * e0.x, Fi0 * f0.x), fmaxf(Ei0 * e0.y, Fi0 * f0.y), \
                       fmaxf(Ei0 * e0.z, Fi0 * f0.z), fmaxf(Ei0 * e0.w, Fi0 * f0.w), \
                       fmaxf(Ei0 * e1.x, Fi0 * f1.x), fmaxf(Ei0 * e1.y, Fi0 * f1.y), \
                       fmaxf(Ei0 * e1.z, Fi0 * f1.z), fmaxf(Ei0 * e1.w, Fi0 * f1.w)}; \
        _Pragma("unroll")                                                            \
        for (int q = 0; q < 4; ++q) {                                                \
            u32 m0 = (u32)(-(int)((byt >> (2 * q)) & 1u));                           \
            u32 m1 = (u32)(-(int)((byt >> (2 * q + 1)) & 1u));                       \
            float p0 = __uint_as_float(__float_as_uint(pA[2 * q]) & m0);             \
            float p1 = __uint_as_float(__float_as_uint(pA[2 * q + 1]) & m1);         \
            asm("v_cvt_pk_bf16_f32 %0, %1, %2" : "=v"(AF.u[q]) : "v"(p0), "v"(p1));  \
        }                                                                            \
    }

#define COMPUTE(JC, CUR, JCL, W0)                                                    \
    {                                                                                \
        const float* ejp = Ej + ((JC) << 5) + (lg << 3);                             \
        const float* fjp = Fj + ((JC) << 5) + (lg << 3);                             \
        float4 e0 = *(const float4*)ejp, e1 = *(const float4*)(ejp + 4);             \
        float4 f0 = *(const float4*)fjp, f1 = *(const float4*)(fjp + 4);             \
        AFu af0;                                                                     \
        PHALF(af0, W0)                                                               \
        _Pragma("unroll")                                                            \
        for (int tc = 0; tc < 8; ++tc) {                                             \
            short8 bfr = *(const short8*)(&Bbuf[CUR][(JCL) * 4096 + tc * 512 + l * 8]); \
            acc[tc] = __builtin_amdgcn_mfma_f32_16x16x32_bf16(af0.s, bfr, acc[tc], 0, 0, 0); \
        }                                                                            \
        accd = __builtin_amdgcn_mfma_f32_16x16x32_bf16(af0.s, bone, accd, 0, 0, 0);  \
    }

#define ATTN_MAIN_LOOP                                                               \
    for (int c = 0; c < 8; ++c) {                                                    \
        int cur = c & 1;                                                             \
        if (c < 7) {                                                                 \
            gload_lds16(wbase + (c + 1) * 16384 + (wv << 10) + l * 8,       &Bbuf[cur ^ 1][(wv << 10)]);       \
            gload_lds16(wbase + (c + 1) * 16384 + (wv << 10) + 512 + l * 8, &Bbuf[cur ^ 1][(wv << 10) + 512]); \
        }                                                                            \
        u32 nw0 = 0, nw1 = 0, nw2 = 0, nw3 = 0;                                      \
        if (c < 7) {                                                                 \
            const u32* mp = mbase + ((4 * c + 4) << 10);                             \
            nw0 = mp[rb + lr];        nw1 = mp[1024 + rb + lr];                      \
            nw2 = mp[2048 + rb + lr]; nw3 = mp[3072 + rb + lr];                      \
        }                                                                            \
        COMPUTE(4 * c,     cur, 0, mw0)                                              \
        COMPUTE(4 * c + 1, cur, 1, mw1)                                              \
        COMPUTE(4 * c + 2, cur, 2, mw2)                                              \
        COMPUTE(4 * c + 3, cur, 3, mw3)                                              \
        mw0 = nw0; mw1 = nw1; mw2 = nw2; mw3 = nw3;                                  \
        __syncthreads();                                                             \
    }

// h store: wave-private 4KB tile in Hls[wv], swizzled. row=(lg<<2)+r, col=tc*16+lr.
#define EPI_STORE_H                                                                  \
    {                                                                                \
        float inv[4];                                                                \
        _Pragma("unroll")                                                            \
        for (int r = 0; r < 4; ++r) inv[r] = 1.f / accd[r];                          \
        _Pragma("unroll")                                                            \
        for (int tc = 0; tc < 8; ++tc)                                               \
            _Pragma("unroll")                                                        \
            for (int r = 0; r < 4; ++r) {                                            \
                float v = acc[tc][r] * inv[r];                                       \
                v = v > 0.f ? v : (__expf(v) - 1.f);                                 \
                v = v > 0.f ? v : (__expf(v) - 1.f);                                 \
                int row = (lg << 2) + r;                                             \
                int col = (tc << 4) + lr;                                            \
                hb[(row << 7) + (col ^ ((row & 7) << 3))] = f2b(v);                  \
            }                                                                        \
    }

// ---------------- attn layer 1 + FUSED projB: outputs Wh2 frag-linear + s2 vectors ----------------
__global__ __launch_bounds__(1024, 1) void k_attnH(const u16* __restrict__ WhT, const float* __restrict__ ssrc,
                                                   const float* __restrict__ sdst, const u32* __restrict__ bmT,
                                                   const u16* __restrict__ W2T, const float* __restrict__ a2,
                                                   u16* __restrict__ Wh2, float* __restrict__ s2s,
                                                   float* __restrict__ s2d) {
    ATTN_PROLOGUE
    ATTN_MAIN_LOOP

    u16* hb = &Hls[wv][0];
    EPI_STORE_H

    // projB: Wh2[rows rb..rb+15] = h @ W2, frag-linear write + rank-1 s2 reductions
    {
        float ps[4], pd[4];
#pragma unroll
        for (int r = 0; r < 4; ++r) { ps[r] = 0.f; pd[r] = 0.f; }
        int jc2 = rb >> 5;
        int lgf = ((wv & 1) << 1) + (lg >> 1);
        u16* wout = Wh2 + (size_t)bt * 131072 + jc2 * 4096;
#pragma unroll
        for (int half = 0; half < 2; ++half) {
            f32x4 accg[4];
#pragma unroll
            for (int tq = 0; tq < 4; ++tq) accg[tq] = (f32x4){0.f, 0.f, 0.f, 0.f};
#pragma unroll
            for (int ch = 0; ch < 4; ++ch) {
                short8 af2 = *(const short8*)(hb + (lr << 7) + (((ch << 5) + (lg << 3)) ^ ((lr & 7) << 3)));
#pragma unroll
                for (int tq = 0; tq < 4; ++tq) {
                    int tc2 = (half << 2) + tq;
                    short8 bf = *(const short8*)(W2T + ((16 * tc2 + lr) << 7) + (ch << 5) + 8 * lg);
                    accg[tq] = __builtin_amdgcn_mfma_f32_16x16x32_bf16(af2, bf, accg[tq], 0, 0, 0);
                }
            }
#pragma unroll
            for (int tq = 0; tq < 4; ++tq) {
                int tc2 = (half << 2) + tq;
                float a2sv = a2[16 * tc2 + lr];
                float a2dv = a2[128 + 16 * tc2 + lr];
                short4v w4;
#pragma unroll
                for (int r = 0; r < 4; ++r) {
                    float wval = accg[tq][r];
                    ps[r] = __builtin_fmaf(wval, a2sv, ps[r]);
                    pd[r] = __builtin_fmaf(wval, a2dv, pd[r]);
                    w4[r] = (short)f2b(wval);
                }
                *(short4v*)(wout + tc2 * 512 + lgf * 128 + lr * 8 + (lg & 1) * 4) = w4;
            }
        }
#pragma unroll
        for (int r = 0; r < 4; ++r) {
#pragma unroll
            for (int o = 1; o < 16; o <<= 1) {
                ps[r] += __shfl_xor(ps[r], o);
                pd[r] += __shfl_xor(pd[r], o);
            }
        }
        if (lr == 0) {
#pragma unroll
            for (int r = 0; r < 4; ++r) {
                int row = rb + 4 * lg + r;
                s2s[(bt << 10) + row] = ps[r];
                s2d[(bt << 10) + row] = pd[r];
            }
        }
    }
}

// ---------------- attn layer 2: fused Gx = elu2(h) @ W_ih^T + bias ----------------
__global__ __launch_bounds__(1024, 1) void k_attnG(const u16* __restrict__ WhT, const float* __restrict__ ssrc,
                                                   const float* __restrict__ sdst, const u32* __restrict__ bmT,
                                                   const u16* __restrict__ WihB, const float* __restrict__ bsum,
                                                   u16* __restrict__ Gx) {
    ATTN_PROLOGUE
    ATTN_MAIN_LOOP

    u16* hb = &Hls[wv][0];
    EPI_STORE_H

    int t = bt & 15;
    int grpx = (b << 6) + (rb >> 4);
    u16* gdst = Gx + (size_t)t * 1048576 + (size_t)grpx * 4096 + l * 8;
#pragma unroll
    for (int half = 0; half < 2; ++half) {
        f32x4 accg[8];
#pragma unroll
        for (int tq = 0; tq < 8; ++tq) accg[tq] = (f32x4){0.f, 0.f, 0.f, 0.f};
#pragma unroll
        for (int ch = 0; ch < 4; ++ch) {
            short8 af2 = *(const short8*)(hb + (lr << 7) + (((ch << 5) + (lg << 3)) ^ ((lr & 7) << 3)));
#pragma unroll
            for (int tq = 0; tq < 8; ++tq) {
                int tc = (half << 3) + tq;
                short8 bf = *(const short8*)(WihB + ((16 * tc + lr) << 7) + (ch << 5) + 8 * lg);
                accg[tq] = __builtin_amdgcn_mfma_f32_16x16x32_bf16(af2, bf, accg[tq], 0, 0, 0);
            }
        }
#pragma unroll
        for (int qq = 0; qq < 4; ++qq) {
            int tc0 = (half << 3) + 2 * qq;
            short8 v;
#pragma unroll
            for (int r = 0; r < 4; ++r) {
                v[r]     = (short)f2b(accg[2 * qq][r]     + bsum[(tc0 << 4) + lr]);
                v[4 + r] = (short)f2b(accg[2 * qq + 1][r] + bsum[((tc0 + 1) << 4) + lr]);
            }
            *(short8*)(gdst + ((half << 2) + qq) * 512) = v;
        }
    }
}

#undef ATTN_PROLOGUE
#undef ATTN_MAIN_LOOP
#undef PHALF
#undef COMPUTE
#undef EPI_STORE_H

// ---------------- LSTM recurrence: 4 waves/block, wave w owns gate-tiles {w,w+4,w+8,w+12}
// (= i/f/g/o for hidden cols [16w,16w+16)); h exchanged via LDS; fused MLP on wave 0 ----------------
__global__ __launch_bounds__(256, 1) void k_lstm(const u16* __restrict__ Gx, const u16* __restrict__ WhhB,
                                                 const float* __restrict__ Wo1, const float* __restrict__ bo1,
                                                 const float* __restrict__ Wo2, const float* __restrict__ bo2,
                                                 float* __restrict__ out) {
    __shared__ u16 hls[16 * 72];
    __shared__ float hf[16 * 65];
    __shared__ float wo1[64 * 32];
    __shared__ float wo2[32];
    int grp = blockIdx.x;
    int m0 = grp << 4;
    int tid = threadIdx.x, wv = tid >> 6, l = tid & 63;
    int lr = l & 15, lg = l >> 4;
    for (int k = tid; k < 64 * 32; k += 256) wo1[k] = Wo1[k];
    if (tid < 32) wo2[tid] = Wo2[tid];
    for (int k = tid; k < 16 * 72; k += 256) hls[k] = 0;
    short8 bh[4][2];
#pragma unroll
    for (int tq = 0; tq < 4; ++tq)
#pragma unroll
        for (int ch = 0; ch < 2; ++ch)
            bh[tq][ch] = *(const short8*)(WhhB + ((16 * (wv + 4 * tq) + lr) << 6) + 32 * ch + 8 * lg);
    float cst[4], hreg[4];
#pragma unroll
    for (int r = 0; r < 4; ++r) { cst[r] = 0.f; hreg[r] = 0.f; }
    int sub = wv & 1;
    // Gx fragments for this wave: q = (wv>>1) + 2*tq
    const u16* gp = Gx + ((size_t)grp << 12) + ((size_t)(wv >> 1) << 9) + l * 8;
    short8 gx0[4], gx1[4];
#pragma unroll
    for (int tq = 0; tq < 4; ++tq) gx0[tq] = *(const short8*)(gp + tq * 1024);
    __syncthreads();
#pragma unroll
    for (int t = 0; t < TT; ++t) {
        if (t < 15) {     // prefetch next step's fragments
#pragma unroll
            for (int tq = 0; tq < 4; ++tq) {
                short8 v = *(const short8*)(gp + (size_t)(t + 1) * 1048576 + tq * 1024);
                if (t & 1) gx0[tq] = v; else gx1[tq] = v;
            }
        }
        f32x4 acc[4];
#pragma unroll
        for (int tq = 0; tq < 4; ++tq) {
            short8 v = (t & 1) ? gx1[tq] : gx0[tq];
#pragma unroll
            for (int r = 0; r < 4; ++r)
                acc[tq][r] = b2f((u16)v[(sub << 2) + r]);
        }
#pragma unroll
        for (int ch = 0; ch < 2; ++ch) {
            short8 af = *(const short8*)(hls + lr * 72 + 32 * ch + 8 * lg);
#pragma unroll
            for (int tq = 0; tq < 4; ++tq)
                acc[tq] = __builtin_amdgcn_mfma_f32_16x16x32_bf16(af, bh[tq][ch], acc[tq], 0, 0, 0);
        }
#pragma unroll
        for (int r = 0; r < 4; ++r) {
            float iv = fsig(acc[0][r]);
            float fv = fsig(acc[1][r]);
            float gv = ftanh(acc[2][r]);
            float ov = fsig(acc[3][r]);
            float cn = __builtin_fmaf(fv, cst[r], iv * gv);
            cst[r] = cn;
            hreg[r] = ov * ftanh(cn);
        }
        __syncthreads();     // all waves done reading hls
#pragma unroll
        for (int r = 0; r < 4; ++r)
            hls[(4 * lg + r) * 72 + 16 * wv + lr] = f2b(hreg[r]);
        __syncthreads();     // h ready for next step
    }
#pragma unroll
    for (int r = 0; r < 4; ++r)
        hf[(4 * lg + r) * 65 + 16 * wv + lr] = hreg[r];
    __syncthreads();
    if (wv == 0) {
        int r = lr, p = lg;
        float hid[8];
#pragma unroll
        for (int q = 0; q < 8; ++q) hid[q] = bo1[8 * p + q];
        for (int j = 0; j < 64; ++j) {
            float hv = hf[r * 65 + j];
#pragma unroll
            for (int q = 0; q < 8; ++q) hid[q] += hv * wo1[j * 32 + 8 * p + q];
        }
        float po = 0.f;
#pragma unroll
        for (int q = 0; q < 8; ++q) po += fmaxf(hid[q], 0.f) * wo2[8 * p + q];
        po += __shfl_xor(po, 16);
        po += __shfl_xor(po, 32);
        if (p == 0) out[m0 + r] = po + bo2[0];
    }
}

extern "C" void kernel_launch(void* const* d_in, const int* in_sizes, int n_in,
                              void* d_out, int out_size, void* d_ws, size_t ws_size,
                              hipStream_t stream) {
    const float* x    = (const float*)d_in[0];
    const int*   adj  = (const int*)d_in[1];
    const float* W1   = (const float*)d_in[2];
    const float* a1   = (const float*)d_in[3];
    const float* W2   = (const float*)d_in[4];
    const float* a2   = (const float*)d_in[5];
    const float* W_ih = (const float*)d_in[6];
    const float* W_hh = (const float*)d_in[7];
    const float* b_ih = (const float*)d_in[8];
    const float* b_hh = (const float*)d_in[9];
    const float* Wo1  = (const float*)d_in[10];
    const float* bo1  = (const float*)d_in[11];
    const float* Wo2  = (const float*)d_in[12];
    const float* bo2  = (const float*)d_in[13];
    float* out = (float*)d_out;

    char* w = (char*)d_ws;
    const size_t SLOT = (size_t)8388608 * sizeof(u16);   // 16.78 MB
    u16* A  = (u16*)w;
    u16* Bf = (u16*)(w + SLOT);
    u16* C  = (u16*)(w + 2 * SLOT);
    char* sm = w + 3 * SLOT;
    float* s1s = (float*)sm;
    float* s1d = s1s + 65536;
    float* s2s = s1d + 65536;
    float* s2d = s2s + 65536;
    u32* BM  = (u32*)(s2d + 65536);      // 131072 words (512 KB), transposed layout
    u16* W1T = (u16*)(BM + 131072);      // 4096
    u16* W2T = W1T + 4096;               // 16384
    u16* WihB = W2T + 16384;             // 32768
    u16* WhhB = WihB + 32768;            // 16384
    float* BS = (float*)(WhhB + 16384);  // 256
    u16* Gx = Bf;                        // Bf free (attnH no longer writes h)

    k_pre<<<64, 256, 0, stream>>>(W1, W2, W_ih, W_hh, b_ih, b_hh, W1T, W2T, WihB, WhhB, BS);
    k_mask<<<1024, 256, 0, stream>>>(adj, BM);
    k_projA<<<1024, 256, 0, stream>>>(x, W1T, a1, A, s1s, s1d);
    k_attnH<<<256, 1024, 0, stream>>>(A, s1s, s1d, BM, W2T, a2, C, s2s, s2d);
    k_attnG<<<256, 1024, 0, stream>>>(C, s2s, s2d, BM, WihB, BS, Gx);
    k_lstm<<<256, 256, 0, stream>>>(Gx, WhhB, Wo1, bo1, Wo2, bo2, out);
}